// Round 5
// baseline (472.754 us; speedup 1.0000x reference)
//
#include <hip/hip_runtime.h>
#include <stdint.h>

// Problem constants
#define E_DIM 1024
#define KAUG 1056            // 1024 + 16 (LoRA) + 1 (bias) + 15 pad
#define N_HEADS 16
#define HD 64
#define R_LORA 16
#define T_LEN 2048
#define B_SZ 2
#define S_LEN 2048
#define NROW 4096            // T*B == S*B
// q pre-scale: (1/sqrt(64)) * log2(e)  -> softmax becomes exp2(score)
#define Q_SCALE 0.1803368801111204f

#define XG_N ((size_t)NROW * KAUG)
#define WG_N ((size_t)E_DIM * KAUG)
#define HSZ  ((size_t)B_SZ * N_HEADS * T_LEN * HD)

typedef unsigned short USH;
typedef __bf16 bf16x8 __attribute__((ext_vector_type(8)));
typedef float  f32x4  __attribute__((ext_vector_type(4)));

__device__ __forceinline__ USH f2bf(float f) {
    uint32_t u = __builtin_bit_cast(uint32_t, f);
    return (USH)((u + 0x7FFFu + ((u >> 16) & 1u)) >> 16);
}
__device__ __forceinline__ float bf2f(USH s) {
    uint32_t u = ((uint32_t)s) << 16;
    return __builtin_bit_cast(float, u);
}
__device__ __forceinline__ void async_cp16(const void* g, void* l) {
    __builtin_amdgcn_global_load_lds(
        (const __attribute__((address_space(1))) void*)g,
        (__attribute__((address_space(3))) void*)l, 16, 0, 0);
}
// pack hi16(x), hi16(y) -> dword (bf16 truncation; y in high half)
__device__ __forceinline__ uint32_t pack_bf_trunc(float x, float y) {
    return __builtin_amdgcn_perm(__builtin_bit_cast(uint32_t, y),
                                 __builtin_bit_cast(uint32_t, x), 0x07060302u);
}

// ---------------------------------------------------------------------------
// Fused q/k/v: write bf16(X) row into Xg[y] AND compute XA tail. grid (NROW,3)
// ---------------------------------------------------------------------------
__global__ __launch_bounds__(256) void lora_aug_x3_kernel(
    const float* __restrict__ Xq, const float* __restrict__ Xk,
    const float* __restrict__ Xv,
    const float* __restrict__ laq, const float* __restrict__ lak,
    const float* __restrict__ lav, USH* __restrict__ Xg_base) {
    int n = blockIdx.x, y = blockIdx.y, tid = threadIdx.x;
    const float* X  = (y == 0) ? Xq : (y == 1) ? Xk : Xv;
    const float* la = (y == 0) ? laq : (y == 1) ? lak : lav;
    USH* Xg = Xg_base + (size_t)y * XG_N;

    float4 xv = *(const float4*)(X + (size_t)n * E_DIM + tid * 4);
    ushort4 ox;
    ox.x = f2bf(xv.x); ox.y = f2bf(xv.y); ox.z = f2bf(xv.z); ox.w = f2bf(xv.w);
    *(ushort4*)(Xg + (size_t)n * KAUG + tid * 4) = ox;

    float acc[R_LORA];
#pragma unroll
    for (int r = 0; r < R_LORA; ++r) {
        float4 lv = *(const float4*)(la + (size_t)r * E_DIM + tid * 4);
        acc[r] = xv.x * lv.x + xv.y * lv.y + xv.z * lv.z + xv.w * lv.w;
    }
#pragma unroll
    for (int r = 0; r < R_LORA; ++r) {
        float v = acc[r];
#pragma unroll
        for (int off = 32; off > 0; off >>= 1) v += __shfl_down(v, off, 64);
        acc[r] = v;
    }
    __shared__ float red[R_LORA][4];
    int lane = tid & 63, wid = tid >> 6;
    if (lane == 0) {
#pragma unroll
        for (int r = 0; r < R_LORA; ++r) red[r][wid] = acc[r];
    }
    __syncthreads();
    if (tid < 32) {
        float v = 0.0f;
        if (tid < R_LORA) v = red[tid][0] + red[tid][1] + red[tid][2] + red[tid][3];
        else if (tid == R_LORA) v = 1.0f;
        Xg[(size_t)n * KAUG + 1024 + tid] = f2bf(v);
    }
}

// ---------------------------------------------------------------------------
// LoRA-A over bf16 rows of Xg (cols 0..1023); writes tail cols 1024..1055.
// ---------------------------------------------------------------------------
__global__ __launch_bounds__(256) void lora_a_bf16_kernel(
    USH* __restrict__ Xg, const float* __restrict__ la) {
    int n = blockIdx.x, tid = threadIdx.x;
    ushort4 xu = *(const ushort4*)(Xg + (size_t)n * KAUG + tid * 4);
    float x0 = bf2f(xu.x), x1 = bf2f(xu.y), x2 = bf2f(xu.z), x3 = bf2f(xu.w);
    float acc[R_LORA];
#pragma unroll
    for (int r = 0; r < R_LORA; ++r) {
        float4 lv = *(const float4*)(la + (size_t)r * E_DIM + tid * 4);
        acc[r] = x0 * lv.x + x1 * lv.y + x2 * lv.z + x3 * lv.w;
    }
#pragma unroll
    for (int r = 0; r < R_LORA; ++r) {
        float v = acc[r];
#pragma unroll
        for (int off = 32; off > 0; off >>= 1) v += __shfl_down(v, off, 64);
        acc[r] = v;
    }
    __shared__ float red[R_LORA][4];
    int lane = tid & 63, wid = tid >> 6;
    if (lane == 0) {
#pragma unroll
        for (int r = 0; r < R_LORA; ++r) red[r][wid] = acc[r];
    }
    __syncthreads();
    if (tid < 32) {
        float v = 0.0f;
        if (tid < R_LORA) v = red[tid][0] + red[tid][1] + red[tid][2] + red[tid][3];
        else if (tid == R_LORA) v = 1.0f;
        Xg[(size_t)n * KAUG + 1024 + tid] = f2bf(v);
    }
}

// ---------------------------------------------------------------------------
// Fused weight augment for all four projections. grid (E_DIM, 4): q,k,v,o.
// ---------------------------------------------------------------------------
__global__ __launch_bounds__(256) void aug_w4_kernel(
    const float* __restrict__ Wq, const float* __restrict__ lbq, const float* __restrict__ bq,
    const float* __restrict__ Wk, const float* __restrict__ lbk, const float* __restrict__ bk_,
    const float* __restrict__ Wv, const float* __restrict__ lbv, const float* __restrict__ bv_,
    const float* __restrict__ Wo, const float* __restrict__ lbo, const float* __restrict__ bo,
    USH* __restrict__ Wg_base) {
    int e = blockIdx.x, y = blockIdx.y, tid = threadIdx.x;
    const float* W    = (y == 0) ? Wq : (y == 1) ? Wk : (y == 2) ? Wv : Wo;
    const float* lb   = (y == 0) ? lbq : (y == 1) ? lbk : (y == 2) ? lbv : lbo;
    const float* bias = (y == 0) ? bq : (y == 1) ? bk_ : (y == 2) ? bv_ : bo;
    USH* Wg = Wg_base + (size_t)y * WG_N;

    float4 v = *(const float4*)(W + (size_t)e * E_DIM + tid * 4);
    ushort4 o;
    o.x = f2bf(v.x); o.y = f2bf(v.y); o.z = f2bf(v.z); o.w = f2bf(v.w);
    *(ushort4*)(Wg + (size_t)e * KAUG + tid * 4) = o;
    if (tid < 32) {
        float t = (tid < R_LORA) ? lb[(size_t)e * R_LORA + tid]
                                 : (tid == R_LORA ? bias[e] : 0.0f);
        Wg[(size_t)e * KAUG + 1024 + tid] = f2bf(t);
    }
}

// ---------------------------------------------------------------------------
// Batched q/k/v GEMM, 128x128 tile (16 MFMA/iter), grid (8, 32, 3) = 768.
// z=0 -> qp [b][h][t][d] * Q_SCALE; z=1 -> kp [b][h][t][d]; z=2 -> vpt [b][h][d][s]
// XCD-chunked swizzle: 96 blocks/XCD.
// ---------------------------------------------------------------------------
__global__ __launch_bounds__(256) void gemm_qkv_kernel(
    const USH* __restrict__ Xg_base, const USH* __restrict__ Wg_base,
    USH* __restrict__ qkv_base) {
    __shared__ __align__(16) USH As[128 * 32];
    __shared__ __align__(16) USH Bs[128 * 32];

    int orig = blockIdx.x + (blockIdx.y << 3) + blockIdx.z * 256;   // grid 8x32x3
    int v_ = (orig & 7) * 96 + (orig >> 3);                          // bijective, 768%8==0
    int e0 = (v_ & 7) * 128, n0 = ((v_ >> 3) & 31) * 128, z = v_ >> 8;

    const USH* Xg = Xg_base + (size_t)z * XG_N;
    const USH* Wg = Wg_base + (size_t)z * WG_N;
    USH* out = qkv_base + (size_t)z * HSZ;
    float scale = (z == 0) ? Q_SCALE : 1.0f;

    int tid = threadIdx.x;
    int wid = tid >> 6, lane = tid & 63, quad = lane >> 4, l16 = lane & 15;
    int wm = wid & 1, wn = wid >> 1;

    int r0 = wid * 16 + (lane >> 2);
    int k8 = (lane & 3) * 8;

    f32x4 acc[4][4];
    const f32x4 fzero = {0.f, 0.f, 0.f, 0.f};
#pragma unroll
    for (int i = 0; i < 4; ++i)
#pragma unroll
        for (int j = 0; j < 4; ++j) acc[i][j] = fzero;

    for (int kt = 0; kt < KAUG; kt += 32) {
        __syncthreads();
        async_cp16(Xg + (size_t)(n0 + r0) * KAUG + kt + k8,       As + (wid * 16) * 32);
        async_cp16(Xg + (size_t)(n0 + 64 + r0) * KAUG + kt + k8,  As + (64 + wid * 16) * 32);
        async_cp16(Wg + (size_t)(e0 + r0) * KAUG + kt + k8,       Bs + (wid * 16) * 32);
        async_cp16(Wg + (size_t)(e0 + 64 + r0) * KAUG + kt + k8,  Bs + (64 + wid * 16) * 32);
        __syncthreads();

        bf16x8 af[4], bfr[4];
#pragma unroll
        for (int i = 0; i < 4; ++i)
            af[i] = *(const bf16x8*)&As[(wm * 64 + i * 16 + l16) * 32 + quad * 8];
#pragma unroll
        for (int j = 0; j < 4; ++j)
            bfr[j] = *(const bf16x8*)&Bs[(wn * 64 + j * 16 + l16) * 32 + quad * 8];
#pragma unroll
        for (int i = 0; i < 4; ++i)
#pragma unroll
            for (int j = 0; j < 4; ++j)
                acc[i][j] = __builtin_amdgcn_mfma_f32_16x16x32_bf16(
                    af[i], bfr[j], acc[i][j], 0, 0, 0);
    }

#pragma unroll
    for (int i = 0; i < 4; ++i) {
#pragma unroll
        for (int j = 0; j < 4; ++j) {
#pragma unroll
            for (int r = 0; r < 4; ++r) {
                int nr = n0 + wm * 64 + i * 16 + quad * 4 + r;
                int ec = e0 + wn * 64 + j * 16 + l16;
                float v = acc[i][j][r] * scale;
                int b = nr & 1, h = ec >> 6, d = ec & 63;
                if (z != 2) {
                    int t = nr >> 1;
                    out[(((size_t)(b * 16 + h) * T_LEN + t) << 6) + d] = f2bf(v);
                } else {
                    int s = nr >> 1;
                    out[(((size_t)(b * 16 + h) * HD + d) << 11) + s] = f2bf(v);
                }
            }
        }
    }
}

// ---------------------------------------------------------------------------
// GEMM mainloop: 64(M) x 128(N) tile (for O-projection).
// ---------------------------------------------------------------------------
__device__ __forceinline__ void gemm_mainloop(
    const USH* __restrict__ Xg, const USH* __restrict__ Wg,
    USH* As, USH* Bs, int n0, int e0, f32x4 (&acc)[2][4]) {
    int tid = threadIdx.x;
    int wid = tid >> 6, lane = tid & 63, quad = lane >> 4, l16 = lane & 15;
    int wm = wid & 1, wn = wid >> 1;
    int r0 = wid * 16 + (lane >> 2);
    int k8 = (lane & 3) * 8;

    for (int kt = 0; kt < KAUG; kt += 32) {
        __syncthreads();
        async_cp16(Xg + (size_t)(n0 + r0) * KAUG + kt + k8,       As + (wid * 16) * 32);
        async_cp16(Wg + (size_t)(e0 + r0) * KAUG + kt + k8,       Bs + (wid * 16) * 32);
        async_cp16(Wg + (size_t)(e0 + 64 + r0) * KAUG + kt + k8,  Bs + (64 + wid * 16) * 32);
        __syncthreads();

        bf16x8 af[2], bfr[4];
#pragma unroll
        for (int i = 0; i < 2; ++i)
            af[i] = *(const bf16x8*)&As[(wm * 32 + i * 16 + l16) * 32 + quad * 8];
#pragma unroll
        for (int j = 0; j < 4; ++j)
            bfr[j] = *(const bf16x8*)&Bs[(wn * 64 + j * 16 + l16) * 32 + quad * 8];
#pragma unroll
        for (int i = 0; i < 2; ++i)
#pragma unroll
            for (int j = 0; j < 4; ++j)
                acc[i][j] = __builtin_amdgcn_mfma_f32_16x16x32_bf16(
                    af[i], bfr[j], acc[i][j], 0, 0, 0);
    }
}

// ---------------------------------------------------------------------------
// O-projection GEMM -> fp32 d_out. grid (8, 64) = 512 blocks.
// ---------------------------------------------------------------------------
__global__ __launch_bounds__(256) void gemm_o_kernel(
    const USH* __restrict__ Xg, const USH* __restrict__ Wg,
    float* __restrict__ out) {
    __shared__ __align__(16) USH As[64 * 32];
    __shared__ __align__(16) USH Bs[128 * 32];

    int orig = blockIdx.x + (blockIdx.y << 3);          // grid 8x64
    int v_ = ((orig & 7) << 6) + (orig >> 3);           // 64 blocks/XCD
    int e0 = (v_ & 7) * 128, n0 = (v_ >> 3) * 64;

    int tid = threadIdx.x;
    int wid = tid >> 6, lane = tid & 63, quad = lane >> 4, l16 = lane & 15;
    int wm = wid & 1, wn = wid >> 1;

    f32x4 acc[2][4];
    const f32x4 fzero = {0.f, 0.f, 0.f, 0.f};
#pragma unroll
    for (int i = 0; i < 2; ++i)
#pragma unroll
        for (int j = 0; j < 4; ++j) acc[i][j] = fzero;

    gemm_mainloop(Xg, Wg, As, Bs, n0, e0, acc);

#pragma unroll
    for (int i = 0; i < 2; ++i)
#pragma unroll
        for (int j = 0; j < 4; ++j)
#pragma unroll
            for (int r = 0; r < 4; ++r) {
                int nr = n0 + wm * 32 + i * 16 + quad * 4 + r;
                int ec = e0 + wn * 64 + j * 16 + l16;
                out[(size_t)nr * E_DIM + ec] = acc[i][j][r];
            }
}

// ---------------------------------------------------------------------------
// Flash v11 = v9 (74.7us, 4 waves/SIMD) + V-direct-to-register.
// v10's regression was the 2-wave/SIMD TLP cut, not V-direct itself: here V
// fragments load global->reg AT 4 waves/SIMD, issued right after QK so the
// softmax/pack phase (~200cyc) covers L1/L2 latency. V tile is shared by all
// 4 waves and same-CU blocks are same-head (XCD chunk) -> L1-resident.
// LDS/wave-iter 20KB -> 12KB; LDS/block 40 -> 24KB. K stays LDS-dbuf (block
// broadcast), one barrier/iter. lbuf now stores 1/lsum for attnw.
// grid (T/64, B*H) = 1024 blocks, 256 thr, 4 blocks/CU.
// ---------------------------------------------------------------------------
__global__ __launch_bounds__(256, 4) void flash_mfma_kernel(
    const USH* __restrict__ qp, const USH* __restrict__ kp,
    const USH* __restrict__ vpt, USH* __restrict__ ohg,
    float* __restrict__ lbuf) {
    __shared__ __align__(16) USH QPs[4096];     // Q tile 64x64, then P blobs
    __shared__ __align__(16) USH Ks[2][4096];   // double-buffered K tile 64x64

    int orig = blockIdx.x + (blockIdx.y << 5);  // grid 32x32
    int v_ = ((orig & 7) << 7) + (orig >> 3);   // 128 blocks/XCD chunk
    int t0 = (v_ & 31) * 64, bh = v_ >> 5;      // chunk c -> heads [4c, 4c+4)

    int tid = threadIdx.x, w = tid >> 6, lane = tid & 63;
    int quad = lane >> 4, l16 = lane & 15;
    int sw = l16 & 7;                          // granule xor-swizzle
    size_t headO = (size_t)bh * (T_LEN * HD);

    // prologue: stage Q (wave w -> i-block w) + first K tile in one batch
#pragma unroll
    for (int half = 0; half < 2; ++half) {
        async_cp16(qp + headO + (size_t)(t0 + w * 16 + l16) * HD + half * 32 + quad * 8,
                   QPs + w * 1024 + half * 512);
        async_cp16(kp + headO + (size_t)(w * 16 + l16) * HD + half * 32 + quad * 8,
                   &Ks[0][w * 1024 + half * 512]);
    }
    __syncthreads();

    // register-cache Q fragments (B-operand: B[n=t=l16][k=d=quad*8+j])
    bf16x8 bq[2];
#pragma unroll
    for (int half = 0; half < 2; ++half)
        bq[half] = *(const bf16x8*)&QPs[w * 1024 + half * 512 + quad * 128 + l16 * 8];

    float lsum = 0.f;
    const f32x4 fzero = {0.f, 0.f, 0.f, 0.f};
    f32x4 o[4];
#pragma unroll
    for (int jd = 0; jd < 4; ++jd) o[jd] = fzero;

    for (int s0 = 0; s0 < S_LEN; s0 += 64) {
        int cur = (s0 >> 6) & 1;
        // prefetch next K tile into the other buffer
        if (s0 + 64 < S_LEN) {
#pragma unroll
            for (int half = 0; half < 2; ++half)
                async_cp16(kp + headO + (size_t)(s0 + 64 + w * 16 + l16) * HD + half * 32 + quad * 8,
                           &Ks[cur ^ 1][w * 1024 + half * 512]);
        }

        // K fragments (A-operand: A[m=s=l16][k=d]), same for all 4 waves
        bf16x8 ak[4][2];
#pragma unroll
        for (int j = 0; j < 4; ++j)
#pragma unroll
            for (int half = 0; half < 2; ++half)
                ak[j][half] = *(const bf16x8*)&Ks[cur][j * 1024 + half * 512 + quad * 128 + l16 * 8];

        // QK^T (swapped): sc[j][r] = score(t=l16, s = s0 + j*16 + quad*4 + r)
        f32x4 sc[4];
        __builtin_amdgcn_s_setprio(1);
#pragma unroll
        for (int j = 0; j < 4; ++j) {
            sc[j] = __builtin_amdgcn_mfma_f32_16x16x32_bf16(ak[j][0], bq[0], fzero, 0, 0, 0);
            sc[j] = __builtin_amdgcn_mfma_f32_16x16x32_bf16(ak[j][1], bq[1], sc[j], 0, 0, 0);
        }
        __builtin_amdgcn_s_setprio(0);

        // V fragments direct global->reg (B-operand: B[n=d=l16][k=s]);
        // issued here so softmax/pack below covers the L1/L2 latency
        bf16x8 bv[4][2];
#pragma unroll
        for (int jd = 0; jd < 4; ++jd) {
            const USH* vrow = vpt + headO + (size_t)(jd * 16 + l16) * S_LEN + s0 + quad * 8;
            bv[jd][0] = *(const bf16x8*)vrow;
            bv[jd][1] = *(const bf16x8*)(vrow + 32);
        }

        float ls = 0.f;
#pragma unroll
        for (int j = 0; j < 4; ++j)
#pragma unroll
            for (int r = 0; r < 4; ++r) {
                float p = __builtin_amdgcn_exp2f(sc[j][r]);
                sc[j][r] = p;
                ls += p;
            }
        lsum += ls;
        // pack P row-major and write: granule g holds s = g*8..g*8+7 of row t=l16
        USH* pb = QPs + w * 1024;
#pragma unroll
        for (int j = 0; j < 4; ++j) {
            uint2 dv;
            dv.x = pack_bf_trunc(sc[j][0], sc[j][1]);
            dv.y = pack_bf_trunc(sc[j][2], sc[j][3]);
            int g = (j * 2 + (quad >> 1)) ^ sw;
            *(uint2*)&pb[l16 * 64 + g * 8 + (quad & 1) * 4] = dv;
        }

        // PV: A-frag = P(t=l16, s' = quad*8 + jj + frag*32)
        bf16x8 ap0 = *(const bf16x8*)&pb[l16 * 64 + (quad ^ sw) * 8];
        bf16x8 ap1 = *(const bf16x8*)&pb[l16 * 64 + ((4 + quad) ^ sw) * 8];
        __builtin_amdgcn_s_setprio(1);
#pragma unroll
        for (int jd = 0; jd < 4; ++jd) {
            o[jd] = __builtin_amdgcn_mfma_f32_16x16x32_bf16(ap0, bv[jd][0], o[jd], 0, 0, 0);
            o[jd] = __builtin_amdgcn_mfma_f32_16x16x32_bf16(ap1, bv[jd][1], o[jd], 0, 0, 0);
        }
        __builtin_amdgcn_s_setprio(0);

        // single barrier per iteration: drains K prefetch + releases cur buffer
        __syncthreads();
    }

    // lsum partial per quad (t = l16): reduce across quad bits
    lsum += __shfl_xor(lsum, 16, 64);
    lsum += __shfl_xor(lsum, 32, 64);
    float rinv = 1.0f / lsum;

    int b = bh >> 4, h = bh & 15;
    float inv[4];
#pragma unroll
    for (int r = 0; r < 4; ++r)
        inv[r] = __shfl(rinv, (lane & 48) | (quad * 4 + r), 64);
#pragma unroll
    for (int jd = 0; jd < 4; ++jd)
#pragma unroll
        for (int r = 0; r < 4; ++r) {
            int t = t0 + w * 16 + quad * 4 + r;
            int n = t * 2 + b, e = h * 64 + jd * 16 + l16;
            ohg[(size_t)n * KAUG + e] = f2bf(o[jd][r] * inv[r]);
        }
    if (quad == 0)
        lbuf[(size_t)bh * T_LEN + t0 + w * 16 + l16] = rinv;   // store 1/lsum
}

// ---------------------------------------------------------------------------
// attnw v6: 128t x 64s per block, grid = 1024 blocks. Q direct, K dbuf with
// next-head prefetch, one barrier/head, XCD-chunked swizzle, native exp2.
// lbuf now holds 1/lsum -> no v_rcp chain per head.
// ---------------------------------------------------------------------------
__global__ __launch_bounds__(256, 4) void attnw_mfma_kernel(
    const USH* __restrict__ qp, const USH* __restrict__ kp,
    const float* __restrict__ lbuf, float* __restrict__ aw) {
    __shared__ __align__(16) USH Ks[2][4096];

    int orig = blockIdx.x + (blockIdx.y << 5) + (blockIdx.z << 9);  // grid 32x16x2
    int v_ = ((orig & 7) << 7) + (orig >> 3);                       // 128 blocks/XCD
    int s0 = (v_ & 31) * 64, t0 = ((v_ >> 5) & 15) * 128, b = v_ >> 9;

    int tid = threadIdx.x, w = tid >> 6, lane = tid & 63;
    int quad = lane >> 4, l16 = lane & 15;

    const f32x4 fzero = {0.f, 0.f, 0.f, 0.f};
    f32x4 acc[2][4];
#pragma unroll
    for (int i2 = 0; i2 < 2; ++i2)
#pragma unroll
        for (int j = 0; j < 4; ++j) acc[i2][j] = fzero;

    // prologue: stage K for head 0
    {
        size_t head0 = (size_t)(b * 16) * (T_LEN * HD);
#pragma unroll
        for (int half = 0; half < 2; ++half)
            async_cp16(kp + head0 + (size_t)(s0 + w * 16 + l16) * HD + half * 32 + quad * 8,
                       &Ks[0][w * 1024 + half * 512]);
    }
    __syncthreads();

    for (int h = 0; h < N_HEADS; ++h) {
        int bh = b * 16 + h;
        size_t head = (size_t)bh * (T_LEN * HD);
        int cur = h & 1;

        // prefetch next head's K into the other buffer
        if (h + 1 < N_HEADS) {
            size_t headn = head + (size_t)(T_LEN * HD);
#pragma unroll
            for (int half = 0; half < 2; ++half)
                async_cp16(kp + headn + (size_t)(s0 + w * 16 + l16) * HD + half * 32 + quad * 8,
                           &Ks[cur ^ 1][w * 1024 + half * 512]);
        }

        // Q fragments direct from global (A-operand; rows are wave-private)
        bf16x8 aq[2][2];
#pragma unroll
        for (int i2 = 0; i2 < 2; ++i2) {
            int i = w * 2 + i2;
            const USH* qrow = qp + head + (size_t)(t0 + i * 16 + l16) * HD + quad * 8;
            aq[i2][0] = *(const bf16x8*)qrow;
            aq[i2][1] = *(const bf16x8*)(qrow + 32);
        }

        float il[2][4];
#pragma unroll
        for (int i2 = 0; i2 < 2; ++i2)
#pragma unroll
            for (int r = 0; r < 4; ++r) {
                int t = t0 + w * 32 + i2 * 16 + quad * 4 + r;
                il[i2][r] = lbuf[(size_t)bh * T_LEN + t];   // already 1/lsum
            }

        bf16x8 bk[4][2];
#pragma unroll
        for (int j = 0; j < 4; ++j)
#pragma unroll
            for (int half = 0; half < 2; ++half)
                bk[j][half] = *(const bf16x8*)&Ks[cur][j * 1024 + half * 512 + quad * 128 + l16 * 8];

#pragma unroll
        for (int i2 = 0; i2 < 2; ++i2) {
#pragma unroll
            for (int j = 0; j < 4; ++j) {
                f32x4 s = __builtin_amdgcn_mfma_f32_16x16x32_bf16(aq[i2][0], bk[j][0], fzero, 0, 0, 0);
                s = __builtin_amdgcn_mfma_f32_16x16x32_bf16(aq[i2][1], bk[j][1], s, 0, 0, 0);
#pragma unroll
                for (int r = 0; r < 4; ++r)
                    acc[i2][j][r] += __builtin_amdgcn_exp2f(s[r]) * il[i2][r];
            }
        }

        // single barrier: drains this head's prefetch + releases cur buffer
        __syncthreads();
    }

    const float inv_h = 1.0f / (float)N_HEADS;
#pragma unroll
    for (int i2 = 0; i2 < 2; ++i2)
#pragma unroll
        for (int j = 0; j < 4; ++j)
#pragma unroll
            for (int r = 0; r < 4; ++r) {
                int t = t0 + w * 32 + i2 * 16 + quad * 4 + r;
                aw[(size_t)b * T_LEN * S_LEN + (size_t)t * S_LEN + s0 + j * 16 + l16] =
                    acc[i2][j][r] * inv_h;
            }
}

// ---------------------------------------------------------------------------
extern "C" void kernel_launch(void* const* d_in, const int* in_sizes, int n_in,
                              void* d_out, int out_size, void* d_ws, size_t ws_size,
                              hipStream_t stream) {
    (void)in_sizes; (void)n_in; (void)out_size; (void)ws_size;

    const float* query = (const float*)d_in[0];
    const float* key_  = (const float*)d_in[1];
    const float* value = (const float*)d_in[2];
    const float* q_w = (const float*)d_in[3],  *q_b = (const float*)d_in[4];
    const float* q_la = (const float*)d_in[5], *q_lb = (const float*)d_in[6];
    const float* k_w = (const float*)d_in[7],  *k_b = (const float*)d_in[8];
    const float* k_la = (const float*)d_in[9], *k_lb = (const float*)d_in[10];
    const float* v_w = (const float*)d_in[11], *v_b = (const float*)d_in[12];
    const float* v_la = (const float*)d_in[13], *v_lb = (const float*)d_in[14];
    const float* o_w = (const float*)d_in[15], *o_b = (const float*)d_in[16];
    const float* o_la = (const float*)d_in[17], *o_lb = (const float*)d_in[18];

    USH* Xg   = (USH*)d_ws;                 // 3 * NROW*KAUG
    USH* Wg   = Xg + 3 * XG_N;              // 4 * E_DIM*KAUG
    USH* qkv  = Wg + 4 * WG_N;              // 3 * HSZ
    USH* qp   = qkv;
    USH* kp   = qkv + HSZ;
    USH* vpt  = qkv + 2 * HSZ;
    float* lbuf = (float*)(qkv + 3 * HSZ);

    float* out = (float*)d_out;                       // (T,B,E) fp32
    float* aw  = out + (size_t)T_LEN * B_SZ * E_DIM;  // (B,T,S) fp32

    dim3 blk(256);

    lora_aug_x3_kernel<<<dim3(NROW, 3), blk, 0, stream>>>(
        query, key_, value, q_la, k_la, v_la, Xg);
    aug_w4_kernel<<<dim3(E_DIM, 4), blk, 0, stream>>>(
        q_w, q_lb, q_b, k_w, k_lb, k_b, v_w, v_lb, v_b, o_w, o_lb, o_b, Wg);
    gemm_qkv_kernel<<<dim3(E_DIM / 128, NROW / 128, 3), blk, 0, stream>>>(Xg, Wg, qkv);

    flash_mfma_kernel<<<dim3(T_LEN / 64, B_SZ * N_HEADS), blk, 0, stream>>>(
        qp, kp, vpt, Xg, lbuf);
    attnw_mfma_kernel<<<dim3(S_LEN / 64, T_LEN / 128, B_SZ), blk, 0, stream>>>(
        qp, kp, lbuf, aw);

    lora_a_bf16_kernel<<<NROW, blk, 0, stream>>>(Xg, o_la);
    gemm_o_kernel<<<dim3(E_DIM / 128, NROW / 64), blk, 0, stream>>>(
        Xg, Wg + 3 * WG_N, out);
}

// Round 6
// 389.390 us; speedup vs baseline: 1.2141x; 1.2141x over previous
//
#include <hip/hip_runtime.h>
#include <stdint.h>

// Problem constants
#define E_DIM 1024
#define KAUG 1056            // 1024 + 16 (LoRA) + 1 (bias) + 15 pad
#define N_HEADS 16
#define HD 64
#define R_LORA 16
#define T_LEN 2048
#define B_SZ 2
#define S_LEN 2048
#define NROW 4096            // T*B == S*B
// q pre-scale: (1/sqrt(64)) * log2(e)  -> softmax becomes exp2(score)
#define Q_SCALE 0.1803368801111204f

#define XG_N ((size_t)NROW * KAUG)
#define WG_N ((size_t)E_DIM * KAUG)
#define HSZ  ((size_t)B_SZ * N_HEADS * T_LEN * HD)

typedef unsigned short USH;
typedef __bf16 bf16x8 __attribute__((ext_vector_type(8)));
typedef float  f32x4  __attribute__((ext_vector_type(4)));

__device__ __forceinline__ USH f2bf(float f) {
    uint32_t u = __builtin_bit_cast(uint32_t, f);
    return (USH)((u + 0x7FFFu + ((u >> 16) & 1u)) >> 16);
}
__device__ __forceinline__ float bf2f(USH s) {
    uint32_t u = ((uint32_t)s) << 16;
    return __builtin_bit_cast(float, u);
}
__device__ __forceinline__ void async_cp16(const void* g, void* l) {
    __builtin_amdgcn_global_load_lds(
        (const __attribute__((address_space(1))) void*)g,
        (__attribute__((address_space(3))) void*)l, 16, 0, 0);
}
// pack hi16(x), hi16(y) -> dword (bf16 truncation; y in high half)
__device__ __forceinline__ uint32_t pack_bf_trunc(float x, float y) {
    return __builtin_amdgcn_perm(__builtin_bit_cast(uint32_t, y),
                                 __builtin_bit_cast(uint32_t, x), 0x07060302u);
}

// ---------------------------------------------------------------------------
// Fused q/k/v: write bf16(X) row into Xg[y] AND compute XA tail. grid (NROW,3)
// ---------------------------------------------------------------------------
__global__ __launch_bounds__(256) void lora_aug_x3_kernel(
    const float* __restrict__ Xq, const float* __restrict__ Xk,
    const float* __restrict__ Xv,
    const float* __restrict__ laq, const float* __restrict__ lak,
    const float* __restrict__ lav, USH* __restrict__ Xg_base) {
    int n = blockIdx.x, y = blockIdx.y, tid = threadIdx.x;
    const float* X  = (y == 0) ? Xq : (y == 1) ? Xk : Xv;
    const float* la = (y == 0) ? laq : (y == 1) ? lak : lav;
    USH* Xg = Xg_base + (size_t)y * XG_N;

    float4 xv = *(const float4*)(X + (size_t)n * E_DIM + tid * 4);
    ushort4 ox;
    ox.x = f2bf(xv.x); ox.y = f2bf(xv.y); ox.z = f2bf(xv.z); ox.w = f2bf(xv.w);
    *(ushort4*)(Xg + (size_t)n * KAUG + tid * 4) = ox;

    float acc[R_LORA];
#pragma unroll
    for (int r = 0; r < R_LORA; ++r) {
        float4 lv = *(const float4*)(la + (size_t)r * E_DIM + tid * 4);
        acc[r] = xv.x * lv.x + xv.y * lv.y + xv.z * lv.z + xv.w * lv.w;
    }
#pragma unroll
    for (int r = 0; r < R_LORA; ++r) {
        float v = acc[r];
#pragma unroll
        for (int off = 32; off > 0; off >>= 1) v += __shfl_down(v, off, 64);
        acc[r] = v;
    }
    __shared__ float red[R_LORA][4];
    int lane = tid & 63, wid = tid >> 6;
    if (lane == 0) {
#pragma unroll
        for (int r = 0; r < R_LORA; ++r) red[r][wid] = acc[r];
    }
    __syncthreads();
    if (tid < 32) {
        float v = 0.0f;
        if (tid < R_LORA) v = red[tid][0] + red[tid][1] + red[tid][2] + red[tid][3];
        else if (tid == R_LORA) v = 1.0f;
        Xg[(size_t)n * KAUG + 1024 + tid] = f2bf(v);
    }
}

// ---------------------------------------------------------------------------
// LoRA-A over bf16 rows of Xg (cols 0..1023); writes tail cols 1024..1055.
// ---------------------------------------------------------------------------
__global__ __launch_bounds__(256) void lora_a_bf16_kernel(
    USH* __restrict__ Xg, const float* __restrict__ la) {
    int n = blockIdx.x, tid = threadIdx.x;
    ushort4 xu = *(const ushort4*)(Xg + (size_t)n * KAUG + tid * 4);
    float x0 = bf2f(xu.x), x1 = bf2f(xu.y), x2 = bf2f(xu.z), x3 = bf2f(xu.w);
    float acc[R_LORA];
#pragma unroll
    for (int r = 0; r < R_LORA; ++r) {
        float4 lv = *(const float4*)(la + (size_t)r * E_DIM + tid * 4);
        acc[r] = x0 * lv.x + x1 * lv.y + x2 * lv.z + x3 * lv.w;
    }
#pragma unroll
    for (int r = 0; r < R_LORA; ++r) {
        float v = acc[r];
#pragma unroll
        for (int off = 32; off > 0; off >>= 1) v += __shfl_down(v, off, 64);
        acc[r] = v;
    }
    __shared__ float red[R_LORA][4];
    int lane = tid & 63, wid = tid >> 6;
    if (lane == 0) {
#pragma unroll
        for (int r = 0; r < R_LORA; ++r) red[r][wid] = acc[r];
    }
    __syncthreads();
    if (tid < 32) {
        float v = 0.0f;
        if (tid < R_LORA) v = red[tid][0] + red[tid][1] + red[tid][2] + red[tid][3];
        else if (tid == R_LORA) v = 1.0f;
        Xg[(size_t)n * KAUG + 1024 + tid] = f2bf(v);
    }
}

// ---------------------------------------------------------------------------
// Fused weight augment for all four projections. grid (E_DIM, 4): q,k,v,o.
// ---------------------------------------------------------------------------
__global__ __launch_bounds__(256) void aug_w4_kernel(
    const float* __restrict__ Wq, const float* __restrict__ lbq, const float* __restrict__ bq,
    const float* __restrict__ Wk, const float* __restrict__ lbk, const float* __restrict__ bk_,
    const float* __restrict__ Wv, const float* __restrict__ lbv, const float* __restrict__ bv_,
    const float* __restrict__ Wo, const float* __restrict__ lbo, const float* __restrict__ bo,
    USH* __restrict__ Wg_base) {
    int e = blockIdx.x, y = blockIdx.y, tid = threadIdx.x;
    const float* W    = (y == 0) ? Wq : (y == 1) ? Wk : (y == 2) ? Wv : Wo;
    const float* lb   = (y == 0) ? lbq : (y == 1) ? lbk : (y == 2) ? lbv : lbo;
    const float* bias = (y == 0) ? bq : (y == 1) ? bk_ : (y == 2) ? bv_ : bo;
    USH* Wg = Wg_base + (size_t)y * WG_N;

    float4 v = *(const float4*)(W + (size_t)e * E_DIM + tid * 4);
    ushort4 o;
    o.x = f2bf(v.x); o.y = f2bf(v.y); o.z = f2bf(v.z); o.w = f2bf(v.w);
    *(ushort4*)(Wg + (size_t)e * KAUG + tid * 4) = o;
    if (tid < 32) {
        float t = (tid < R_LORA) ? lb[(size_t)e * R_LORA + tid]
                                 : (tid == R_LORA ? bias[e] : 0.0f);
        Wg[(size_t)e * KAUG + 1024 + tid] = f2bf(t);
    }
}

// ---------------------------------------------------------------------------
// Batched q/k/v GEMM, 128x128 tile, grid (8, 32, 3) = 768. NEW: double-
// buffered LDS + prefetch-before-compute + ONE barrier per K-step (was 2
// barriers with the VMEM drain inside the critical path).
// ---------------------------------------------------------------------------
__global__ __launch_bounds__(256) void gemm_qkv_kernel(
    const USH* __restrict__ Xg_base, const USH* __restrict__ Wg_base,
    USH* __restrict__ qkv_base) {
    __shared__ __align__(16) USH As[2][128 * 32];
    __shared__ __align__(16) USH Bs[2][128 * 32];

    int orig = blockIdx.x + (blockIdx.y << 3) + blockIdx.z * 256;   // grid 8x32x3
    int v_ = (orig & 7) * 96 + (orig >> 3);                          // bijective, 768%8==0
    int e0 = (v_ & 7) * 128, n0 = ((v_ >> 3) & 31) * 128, z = v_ >> 8;

    const USH* Xg = Xg_base + (size_t)z * XG_N;
    const USH* Wg = Wg_base + (size_t)z * WG_N;
    USH* out = qkv_base + (size_t)z * HSZ;
    float scale = (z == 0) ? Q_SCALE : 1.0f;

    int tid = threadIdx.x;
    int wid = tid >> 6, lane = tid & 63, quad = lane >> 4, l16 = lane & 15;
    int wm = wid & 1, wn = wid >> 1;

    int r0 = wid * 16 + (lane >> 2);
    int k8 = (lane & 3) * 8;

    f32x4 acc[4][4];
    const f32x4 fzero = {0.f, 0.f, 0.f, 0.f};
#pragma unroll
    for (int i = 0; i < 4; ++i)
#pragma unroll
        for (int j = 0; j < 4; ++j) acc[i][j] = fzero;

    // prologue: stage kt=0 into buf 0
    async_cp16(Xg + (size_t)(n0 + r0) * KAUG + k8,       As[0] + (wid * 16) * 32);
    async_cp16(Xg + (size_t)(n0 + 64 + r0) * KAUG + k8,  As[0] + (64 + wid * 16) * 32);
    async_cp16(Wg + (size_t)(e0 + r0) * KAUG + k8,       Bs[0] + (wid * 16) * 32);
    async_cp16(Wg + (size_t)(e0 + 64 + r0) * KAUG + k8,  Bs[0] + (64 + wid * 16) * 32);
    __syncthreads();

    int cur = 0;
    for (int kt = 0; kt < KAUG; kt += 32, cur ^= 1) {
        if (kt + 32 < KAUG) {
            int kn = kt + 32;
            async_cp16(Xg + (size_t)(n0 + r0) * KAUG + kn + k8,       As[cur ^ 1] + (wid * 16) * 32);
            async_cp16(Xg + (size_t)(n0 + 64 + r0) * KAUG + kn + k8,  As[cur ^ 1] + (64 + wid * 16) * 32);
            async_cp16(Wg + (size_t)(e0 + r0) * KAUG + kn + k8,       Bs[cur ^ 1] + (wid * 16) * 32);
            async_cp16(Wg + (size_t)(e0 + 64 + r0) * KAUG + kn + k8,  Bs[cur ^ 1] + (64 + wid * 16) * 32);
        }

        bf16x8 af[4], bfr[4];
#pragma unroll
        for (int i = 0; i < 4; ++i)
            af[i] = *(const bf16x8*)&As[cur][(wm * 64 + i * 16 + l16) * 32 + quad * 8];
#pragma unroll
        for (int j = 0; j < 4; ++j)
            bfr[j] = *(const bf16x8*)&Bs[cur][(wn * 64 + j * 16 + l16) * 32 + quad * 8];
#pragma unroll
        for (int i = 0; i < 4; ++i)
#pragma unroll
            for (int j = 0; j < 4; ++j)
                acc[i][j] = __builtin_amdgcn_mfma_f32_16x16x32_bf16(
                    af[i], bfr[j], acc[i][j], 0, 0, 0);

        // one barrier: drains prefetch (landed under compute) + releases cur
        __syncthreads();
    }

#pragma unroll
    for (int i = 0; i < 4; ++i) {
#pragma unroll
        for (int j = 0; j < 4; ++j) {
#pragma unroll
            for (int r = 0; r < 4; ++r) {
                int nr = n0 + wm * 64 + i * 16 + quad * 4 + r;
                int ec = e0 + wn * 64 + j * 16 + l16;
                float v = acc[i][j][r] * scale;
                int b = nr & 1, h = ec >> 6, d = ec & 63;
                if (z != 2) {
                    int t = nr >> 1;
                    out[(((size_t)(b * 16 + h) * T_LEN + t) << 6) + d] = f2bf(v);
                } else {
                    int s = nr >> 1;
                    out[(((size_t)(b * 16 + h) * HD + d) << 11) + s] = f2bf(v);
                }
            }
        }
    }
}

// ---------------------------------------------------------------------------
// O-projection GEMM -> fp32 d_out. grid (8, 64) = 512 blocks. Same pipelined
// single-barrier loop (dbuf LDS: 2x(4+8) = 24 KB).
// ---------------------------------------------------------------------------
__global__ __launch_bounds__(256) void gemm_o_kernel(
    const USH* __restrict__ Xg, const USH* __restrict__ Wg,
    float* __restrict__ out) {
    __shared__ __align__(16) USH As[2][64 * 32];
    __shared__ __align__(16) USH Bs[2][128 * 32];

    int orig = blockIdx.x + (blockIdx.y << 3);          // grid 8x64
    int v_ = ((orig & 7) << 6) + (orig >> 3);           // 64 blocks/XCD
    int e0 = (v_ & 7) * 128, n0 = (v_ >> 3) * 64;

    int tid = threadIdx.x;
    int wid = tid >> 6, lane = tid & 63, quad = lane >> 4, l16 = lane & 15;
    int wm = wid & 1, wn = wid >> 1;
    int r0 = wid * 16 + (lane >> 2);
    int k8 = (lane & 3) * 8;

    f32x4 acc[2][4];
    const f32x4 fzero = {0.f, 0.f, 0.f, 0.f};
#pragma unroll
    for (int i = 0; i < 2; ++i)
#pragma unroll
        for (int j = 0; j < 4; ++j) acc[i][j] = fzero;

    // prologue: stage kt=0 into buf 0
    async_cp16(Xg + (size_t)(n0 + r0) * KAUG + k8,       As[0] + (wid * 16) * 32);
    async_cp16(Wg + (size_t)(e0 + r0) * KAUG + k8,       Bs[0] + (wid * 16) * 32);
    async_cp16(Wg + (size_t)(e0 + 64 + r0) * KAUG + k8,  Bs[0] + (64 + wid * 16) * 32);
    __syncthreads();

    int cur = 0;
    for (int kt = 0; kt < KAUG; kt += 32, cur ^= 1) {
        if (kt + 32 < KAUG) {
            int kn = kt + 32;
            async_cp16(Xg + (size_t)(n0 + r0) * KAUG + kn + k8,       As[cur ^ 1] + (wid * 16) * 32);
            async_cp16(Wg + (size_t)(e0 + r0) * KAUG + kn + k8,       Bs[cur ^ 1] + (wid * 16) * 32);
            async_cp16(Wg + (size_t)(e0 + 64 + r0) * KAUG + kn + k8,  Bs[cur ^ 1] + (64 + wid * 16) * 32);
        }

        bf16x8 af[2], bfr[4];
#pragma unroll
        for (int i = 0; i < 2; ++i)
            af[i] = *(const bf16x8*)&As[cur][(wm * 32 + i * 16 + l16) * 32 + quad * 8];
#pragma unroll
        for (int j = 0; j < 4; ++j)
            bfr[j] = *(const bf16x8*)&Bs[cur][(wn * 64 + j * 16 + l16) * 32 + quad * 8];
#pragma unroll
        for (int i = 0; i < 2; ++i)
#pragma unroll
            for (int j = 0; j < 4; ++j)
                acc[i][j] = __builtin_amdgcn_mfma_f32_16x16x32_bf16(
                    af[i], bfr[j], acc[i][j], 0, 0, 0);

        __syncthreads();
    }

#pragma unroll
    for (int i = 0; i < 2; ++i)
#pragma unroll
        for (int j = 0; j < 4; ++j)
#pragma unroll
            for (int r = 0; r < 4; ++r) {
                int nr = n0 + wm * 32 + i * 16 + quad * 4 + r;
                int ec = e0 + wn * 64 + j * 16 + l16;
                out[(size_t)nr * E_DIM + ec] = acc[i][j][r];
            }
}

// ---------------------------------------------------------------------------
// Flash v12 = v9 + software-pipelined PV (one iteration behind QK).
// P is WAVE-PRIVATE: PV(i-1) reads the P blob BEFORE softmax(i) overwrites
// it -- same-wave DS ordering makes a SINGLE P buffer safe (no extra LDS,
// no extra barrier). V staging shifts one iter late (stage V[i] at iter i,
// consume at i+1) so dbuf indices stay race-free. The P round-trip and all
// PV work leave the QK->softmax critical path; PV MFMAs overlap exp2 VALU.
// Q direct global->reg (attnw-proven). LDS: 8(P) + 16(K) + 16(V) = 40 KB,
// 4 blocks/CU, 4 waves/SIMD. grid (T/64, B*H) = 1024 blocks.
// ---------------------------------------------------------------------------
__global__ __launch_bounds__(256, 4) void flash_mfma_kernel(
    const USH* __restrict__ qp, const USH* __restrict__ kp,
    const USH* __restrict__ vpt, USH* __restrict__ ohg,
    float* __restrict__ lbuf) {
    __shared__ __align__(16) USH Pb[4096];      // P blobs, 1024 USH per wave
    __shared__ __align__(16) USH Ks[2][4096];   // double-buffered K tile 64x64
    __shared__ __align__(16) USH Vs[2][4096];   // double-buffered V^T tile 64x64

    int orig = blockIdx.x + (blockIdx.y << 5);  // grid 32x32
    int v_ = ((orig & 7) << 7) + (orig >> 3);   // 128 blocks/XCD chunk
    int t0 = (v_ & 31) * 64, bh = v_ >> 5;      // chunk c -> heads [4c, 4c+4)

    int tid = threadIdx.x, w = tid >> 6, lane = tid & 63;
    int quad = lane >> 4, l16 = lane & 15;
    int sw = l16 & 7;                          // granule xor-swizzle
    size_t headO = (size_t)bh * (T_LEN * HD);

    // Q fragments direct from global (B-operand: B[n=t=l16][k=d=quad*8+j])
    bf16x8 bq[2];
    {
        const USH* qrow = qp + headO + (size_t)(t0 + w * 16 + l16) * HD + quad * 8;
        bq[0] = *(const bf16x8*)qrow;
        bq[1] = *(const bf16x8*)(qrow + 32);
    }

    // prologue: stage K[0]
#pragma unroll
    for (int half = 0; half < 2; ++half)
        async_cp16(kp + headO + (size_t)(w * 16 + l16) * HD + half * 32 + quad * 8,
                   &Ks[0][w * 1024 + half * 512]);
    __syncthreads();

    float lsum = 0.f;
    const f32x4 fzero = {0.f, 0.f, 0.f, 0.f};
    f32x4 o[4];
#pragma unroll
    for (int jd = 0; jd < 4; ++jd) o[jd] = fzero;

    USH* pb = Pb + w * 1024;

    for (int it = 0; it < S_LEN / 64; ++it) {
        int s0 = it * 64, cur = it & 1;
        // prefetch K[it+1] -> Ks[cur^1]; stage V[it] -> Vs[cur]
        if (it + 1 < S_LEN / 64) {
#pragma unroll
            for (int half = 0; half < 2; ++half)
                async_cp16(kp + headO + (size_t)(s0 + 64 + w * 16 + l16) * HD + half * 32 + quad * 8,
                           &Ks[cur ^ 1][w * 1024 + half * 512]);
        }
#pragma unroll
        for (int half = 0; half < 2; ++half)
            async_cp16(vpt + headO + (size_t)(w * 16 + l16) * S_LEN + s0 + half * 32 + quad * 8,
                       &Vs[cur][w * 1024 + half * 512]);

        // K fragments (A-operand: A[m=s=l16][k=d])
        bf16x8 ak[4][2];
#pragma unroll
        for (int j = 0; j < 4; ++j)
#pragma unroll
            for (int half = 0; half < 2; ++half)
                ak[j][half] = *(const bf16x8*)&Ks[cur][j * 1024 + half * 512 + quad * 128 + l16 * 8];

        // QK^T (swapped): sc[j][r] = score(t=l16, s = s0 + j*16 + quad*4 + r)
        f32x4 sc[4];
        __builtin_amdgcn_s_setprio(1);
#pragma unroll
        for (int j = 0; j < 4; ++j) {
            sc[j] = __builtin_amdgcn_mfma_f32_16x16x32_bf16(ak[j][0], bq[0], fzero, 0, 0, 0);
            sc[j] = __builtin_amdgcn_mfma_f32_16x16x32_bf16(ak[j][1], bq[1], sc[j], 0, 0, 0);
        }
        __builtin_amdgcn_s_setprio(0);

        // PV(it-1): reads P blob (old content, wave-private -> safe before
        // this iter's overwrite) and Vs[(it-1)&1]. Independent of QK's result
        // -> MFMAs and ds_reads overlap the exp2 chain below.
        if (it > 0) {
            bf16x8 ap0 = *(const bf16x8*)&pb[l16 * 64 + (quad ^ sw) * 8];
            bf16x8 ap1 = *(const bf16x8*)&pb[l16 * 64 + ((4 + quad) ^ sw) * 8];
            bf16x8 bv[4][2];
#pragma unroll
            for (int jd = 0; jd < 4; ++jd)
#pragma unroll
                for (int half = 0; half < 2; ++half)
                    bv[jd][half] = *(const bf16x8*)&Vs[cur ^ 1][jd * 1024 + half * 512 + quad * 128 + l16 * 8];
#pragma unroll
            for (int jd = 0; jd < 4; ++jd) {
                o[jd] = __builtin_amdgcn_mfma_f32_16x16x32_bf16(ap0, bv[jd][0], o[jd], 0, 0, 0);
                o[jd] = __builtin_amdgcn_mfma_f32_16x16x32_bf16(ap1, bv[jd][1], o[jd], 0, 0, 0);
            }
        }

        // softmax(it)
        float ls = 0.f;
#pragma unroll
        for (int j = 0; j < 4; ++j)
#pragma unroll
            for (int r = 0; r < 4; ++r) {
                float p = __builtin_amdgcn_exp2f(sc[j][r]);
                sc[j][r] = p;
                ls += p;
            }
        lsum += ls;

        // pack P(it) row-major and write (overwrites blob AFTER the PV read)
#pragma unroll
        for (int j = 0; j < 4; ++j) {
            uint2 dv;
            dv.x = pack_bf_trunc(sc[j][0], sc[j][1]);
            dv.y = pack_bf_trunc(sc[j][2], sc[j][3]);
            int g = (j * 2 + (quad >> 1)) ^ sw;
            *(uint2*)&pb[l16 * 64 + g * 8 + (quad & 1) * 4] = dv;
        }

        // one barrier/iter: drains K[it+1] + V[it] staging, releases buffers
        __syncthreads();
    }

    // epilogue: PV for the last tile (it = 31, Vs[1])
    {
        bf16x8 ap0 = *(const bf16x8*)&pb[l16 * 64 + (quad ^ sw) * 8];
        bf16x8 ap1 = *(const bf16x8*)&pb[l16 * 64 + ((4 + quad) ^ sw) * 8];
        bf16x8 bv[4][2];
#pragma unroll
        for (int jd = 0; jd < 4; ++jd)
#pragma unroll
            for (int half = 0; half < 2; ++half)
                bv[jd][half] = *(const bf16x8*)&Vs[1][jd * 1024 + half * 512 + quad * 128 + l16 * 8];
#pragma unroll
        for (int jd = 0; jd < 4; ++jd) {
            o[jd] = __builtin_amdgcn_mfma_f32_16x16x32_bf16(ap0, bv[jd][0], o[jd], 0, 0, 0);
            o[jd] = __builtin_amdgcn_mfma_f32_16x16x32_bf16(ap1, bv[jd][1], o[jd], 0, 0, 0);
        }
    }

    // lsum partial per quad (t = l16): reduce across quad bits
    lsum += __shfl_xor(lsum, 16, 64);
    lsum += __shfl_xor(lsum, 32, 64);
    float rinv = 1.0f / lsum;

    int b = bh >> 4, h = bh & 15;
    float inv[4];
#pragma unroll
    for (int r = 0; r < 4; ++r)
        inv[r] = __shfl(rinv, (lane & 48) | (quad * 4 + r), 64);
#pragma unroll
    for (int jd = 0; jd < 4; ++jd)
#pragma unroll
        for (int r = 0; r < 4; ++r) {
            int t = t0 + w * 16 + quad * 4 + r;
            int n = t * 2 + b, e = h * 64 + jd * 16 + l16;
            ohg[(size_t)n * KAUG + e] = f2bf(o[jd][r] * inv[r]);
        }
    if (quad == 0)
        lbuf[(size_t)bh * T_LEN + t0 + w * 16 + l16] = rinv;   // store 1/lsum
}

// ---------------------------------------------------------------------------
// attnw v6: 128t x 64s per block, grid = 1024 blocks. Q direct, K dbuf with
// next-head prefetch, one barrier/head, XCD-chunked swizzle, native exp2,
// lbuf holds 1/lsum (no rcp chain). No per-MFMA setprio (m190).
// ---------------------------------------------------------------------------
__global__ __launch_bounds__(256, 4) void attnw_mfma_kernel(
    const USH* __restrict__ qp, const USH* __restrict__ kp,
    const float* __restrict__ lbuf, float* __restrict__ aw) {
    __shared__ __align__(16) USH Ks[2][4096];

    int orig = blockIdx.x + (blockIdx.y << 5) + (blockIdx.z << 9);  // grid 32x16x2
    int v_ = ((orig & 7) << 7) + (orig >> 3);                       // 128 blocks/XCD
    int s0 = (v_ & 31) * 64, t0 = ((v_ >> 5) & 15) * 128, b = v_ >> 9;

    int tid = threadIdx.x, w = tid >> 6, lane = tid & 63;
    int quad = lane >> 4, l16 = lane & 15;

    const f32x4 fzero = {0.f, 0.f, 0.f, 0.f};
    f32x4 acc[2][4];
#pragma unroll
    for (int i2 = 0; i2 < 2; ++i2)
#pragma unroll
        for (int j = 0; j < 4; ++j) acc[i2][j] = fzero;

    // prologue: stage K for head 0
    {
        size_t head0 = (size_t)(b * 16) * (T_LEN * HD);
#pragma unroll
        for (int half = 0; half < 2; ++half)
            async_cp16(kp + head0 + (size_t)(s0 + w * 16 + l16) * HD + half * 32 + quad * 8,
                       &Ks[0][w * 1024 + half * 512]);
    }
    __syncthreads();

    for (int h = 0; h < N_HEADS; ++h) {
        int bh = b * 16 + h;
        size_t head = (size_t)bh * (T_LEN * HD);
        int cur = h & 1;

        // prefetch next head's K into the other buffer
        if (h + 1 < N_HEADS) {
            size_t headn = head + (size_t)(T_LEN * HD);
#pragma unroll
            for (int half = 0; half < 2; ++half)
                async_cp16(kp + headn + (size_t)(s0 + w * 16 + l16) * HD + half * 32 + quad * 8,
                           &Ks[cur ^ 1][w * 1024 + half * 512]);
        }

        // Q fragments direct from global (A-operand; rows are wave-private)
        bf16x8 aq[2][2];
#pragma unroll
        for (int i2 = 0; i2 < 2; ++i2) {
            int i = w * 2 + i2;
            const USH* qrow = qp + head + (size_t)(t0 + i * 16 + l16) * HD + quad * 8;
            aq[i2][0] = *(const bf16x8*)qrow;
            aq[i2][1] = *(const bf16x8*)(qrow + 32);
        }

        float il[2][4];
#pragma unroll
        for (int i2 = 0; i2 < 2; ++i2)
#pragma unroll
            for (int r = 0; r < 4; ++r) {
                int t = t0 + w * 32 + i2 * 16 + quad * 4 + r;
                il[i2][r] = lbuf[(size_t)bh * T_LEN + t];   // already 1/lsum
            }

        bf16x8 bk[4][2];
#pragma unroll
        for (int j = 0; j < 4; ++j)
#pragma unroll
            for (int half = 0; half < 2; ++half)
                bk[j][half] = *(const bf16x8*)&Ks[cur][j * 1024 + half * 512 + quad * 128 + l16 * 8];

#pragma unroll
        for (int i2 = 0; i2 < 2; ++i2) {
#pragma unroll
            for (int j = 0; j < 4; ++j) {
                f32x4 s = __builtin_amdgcn_mfma_f32_16x16x32_bf16(aq[i2][0], bk[j][0], fzero, 0, 0, 0);
                s = __builtin_amdgcn_mfma_f32_16x16x32_bf16(aq[i2][1], bk[j][1], s, 0, 0, 0);
#pragma unroll
                for (int r = 0; r < 4; ++r)
                    acc[i2][j][r] += __builtin_amdgcn_exp2f(s[r]) * il[i2][r];
            }
        }

        // single barrier: drains this head's prefetch + releases cur buffer
        __syncthreads();
    }

    const float inv_h = 1.0f / (float)N_HEADS;
#pragma unroll
    for (int i2 = 0; i2 < 2; ++i2)
#pragma unroll
        for (int j = 0; j < 4; ++j)
#pragma unroll
            for (int r = 0; r < 4; ++r) {
                int t = t0 + w * 32 + i2 * 16 + quad * 4 + r;
                aw[(size_t)b * T_LEN * S_LEN + (size_t)t * S_LEN + s0 + j * 16 + l16] =
                    acc[i2][j][r] * inv_h;
            }
}

// ---------------------------------------------------------------------------
extern "C" void kernel_launch(void* const* d_in, const int* in_sizes, int n_in,
                              void* d_out, int out_size, void* d_ws, size_t ws_size,
                              hipStream_t stream) {
    (void)in_sizes; (void)n_in; (void)out_size; (void)ws_size;

    const float* query = (const float*)d_in[0];
    const float* key_  = (const float*)d_in[1];
    const float* value = (const float*)d_in[2];
    const float* q_w = (const float*)d_in[3],  *q_b = (const float*)d_in[4];
    const float* q_la = (const float*)d_in[5], *q_lb = (const float*)d_in[6];
    const float* k_w = (const float*)d_in[7],  *k_b = (const float*)d_in[8];
    const float* k_la = (const float*)d_in[9], *k_lb = (const float*)d_in[10];
    const float* v_w = (const float*)d_in[11], *v_b = (const float*)d_in[12];
    const float* v_la = (const float*)d_in[13], *v_lb = (const float*)d_in[14];
    const float* o_w = (const float*)d_in[15], *o_b = (const float*)d_in[16];
    const float* o_la = (const float*)d_in[17], *o_lb = (const float*)d_in[18];

    USH* Xg   = (USH*)d_ws;                 // 3 * NROW*KAUG
    USH* Wg   = Xg + 3 * XG_N;              // 4 * E_DIM*KAUG
    USH* qkv  = Wg + 4 * WG_N;              // 3 * HSZ
    USH* qp   = qkv;
    USH* kp   = qkv + HSZ;
    USH* vpt  = qkv + 2 * HSZ;
    float* lbuf = (float*)(qkv + 3 * HSZ);

    float* out = (float*)d_out;                       // (T,B,E) fp32
    float* aw  = out + (size_t)T_LEN * B_SZ * E_DIM;  // (B,T,S) fp32

    dim3 blk(256);

    lora_aug_x3_kernel<<<dim3(NROW, 3), blk, 0, stream>>>(
        query, key_, value, q_la, k_la, v_la, Xg);
    aug_w4_kernel<<<dim3(E_DIM, 4), blk, 0, stream>>>(
        q_w, q_lb, q_b, k_w, k_lb, k_b, v_w, v_lb, v_b, o_w, o_lb, o_b, Wg);
    gemm_qkv_kernel<<<dim3(E_DIM / 128, NROW / 128, 3), blk, 0, stream>>>(Xg, Wg, qkv);

    flash_mfma_kernel<<<dim3(T_LEN / 64, B_SZ * N_HEADS), blk, 0, stream>>>(
        qp, kp, vpt, Xg, lbuf);
    attnw_mfma_kernel<<<dim3(S_LEN / 64, T_LEN / 128, B_SZ), blk, 0, stream>>>(
        qp, kp, lbuf, aw);

    lora_a_bf16_kernel<<<NROW, blk, 0, stream>>>(Xg, o_la);
    gemm_o_kernel<<<dim3(E_DIM / 128, NROW / 64), blk, 0, stream>>>(
        Xg, Wg + 3 * WG_N, out);
}

// Round 7
// 377.257 us; speedup vs baseline: 1.2531x; 1.0322x over previous
//
#include <hip/hip_runtime.h>
#include <stdint.h>

// Problem constants
#define E_DIM 1024
#define KAUG 1056            // 1024 + 16 (LoRA) + 1 (bias) + 15 pad
#define N_HEADS 16
#define HD 64
#define R_LORA 16
#define T_LEN 2048
#define B_SZ 2
#define S_LEN 2048
#define NROW 4096            // T*B == S*B
// q pre-scale: (1/sqrt(64)) * log2(e)  -> softmax becomes exp2(score)
#define Q_SCALE 0.1803368801111204f

#define XG_N ((size_t)NROW * KAUG)
#define WG_N ((size_t)E_DIM * KAUG)
#define HSZ  ((size_t)B_SZ * N_HEADS * T_LEN * HD)

typedef unsigned short USH;
typedef __bf16 bf16x8 __attribute__((ext_vector_type(8)));
typedef float  f32x4  __attribute__((ext_vector_type(4)));
typedef float  f32x16 __attribute__((ext_vector_type(16)));
typedef unsigned int u32x2 __attribute__((ext_vector_type(2)));
typedef unsigned int u32x4 __attribute__((ext_vector_type(4)));

__device__ __forceinline__ USH f2bf(float f) {
    uint32_t u = __builtin_bit_cast(uint32_t, f);
    return (USH)((u + 0x7FFFu + ((u >> 16) & 1u)) >> 16);
}
__device__ __forceinline__ float bf2f(USH s) {
    uint32_t u = ((uint32_t)s) << 16;
    return __builtin_bit_cast(float, u);
}
__device__ __forceinline__ void async_cp16(const void* g, void* l) {
    __builtin_amdgcn_global_load_lds(
        (const __attribute__((address_space(1))) void*)g,
        (__attribute__((address_space(3))) void*)l, 16, 0, 0);
}
// pack hi16(x), hi16(y) -> dword (bf16 truncation; y in high half)
__device__ __forceinline__ uint32_t pack_bf_trunc(float x, float y) {
    return __builtin_amdgcn_perm(__builtin_bit_cast(uint32_t, y),
                                 __builtin_bit_cast(uint32_t, x), 0x07060302u);
}

// ---------------------------------------------------------------------------
// Fused q/k/v: write bf16(X) row into Xg[y] AND compute XA tail. grid (NROW,3)
// ---------------------------------------------------------------------------
__global__ __launch_bounds__(256) void lora_aug_x3_kernel(
    const float* __restrict__ Xq, const float* __restrict__ Xk,
    const float* __restrict__ Xv,
    const float* __restrict__ laq, const float* __restrict__ lak,
    const float* __restrict__ lav, USH* __restrict__ Xg_base) {
    int n = blockIdx.x, y = blockIdx.y, tid = threadIdx.x;
    const float* X  = (y == 0) ? Xq : (y == 1) ? Xk : Xv;
    const float* la = (y == 0) ? laq : (y == 1) ? lak : lav;
    USH* Xg = Xg_base + (size_t)y * XG_N;

    float4 xv = *(const float4*)(X + (size_t)n * E_DIM + tid * 4);
    ushort4 ox;
    ox.x = f2bf(xv.x); ox.y = f2bf(xv.y); ox.z = f2bf(xv.z); ox.w = f2bf(xv.w);
    *(ushort4*)(Xg + (size_t)n * KAUG + tid * 4) = ox;

    float acc[R_LORA];
#pragma unroll
    for (int r = 0; r < R_LORA; ++r) {
        float4 lv = *(const float4*)(la + (size_t)r * E_DIM + tid * 4);
        acc[r] = xv.x * lv.x + xv.y * lv.y + xv.z * lv.z + xv.w * lv.w;
    }
#pragma unroll
    for (int r = 0; r < R_LORA; ++r) {
        float v = acc[r];
#pragma unroll
        for (int off = 32; off > 0; off >>= 1) v += __shfl_down(v, off, 64);
        acc[r] = v;
    }
    __shared__ float red[R_LORA][4];
    int lane = tid & 63, wid = tid >> 6;
    if (lane == 0) {
#pragma unroll
        for (int r = 0; r < R_LORA; ++r) red[r][wid] = acc[r];
    }
    __syncthreads();
    if (tid < 32) {
        float v = 0.0f;
        if (tid < R_LORA) v = red[tid][0] + red[tid][1] + red[tid][2] + red[tid][3];
        else if (tid == R_LORA) v = 1.0f;
        Xg[(size_t)n * KAUG + 1024 + tid] = f2bf(v);
    }
}

// ---------------------------------------------------------------------------
// LoRA-A over bf16 rows of Xg (cols 0..1023); writes tail cols 1024..1055.
// ---------------------------------------------------------------------------
__global__ __launch_bounds__(256) void lora_a_bf16_kernel(
    USH* __restrict__ Xg, const float* __restrict__ la) {
    int n = blockIdx.x, tid = threadIdx.x;
    ushort4 xu = *(const ushort4*)(Xg + (size_t)n * KAUG + tid * 4);
    float x0 = bf2f(xu.x), x1 = bf2f(xu.y), x2 = bf2f(xu.z), x3 = bf2f(xu.w);
    float acc[R_LORA];
#pragma unroll
    for (int r = 0; r < R_LORA; ++r) {
        float4 lv = *(const float4*)(la + (size_t)r * E_DIM + tid * 4);
        acc[r] = x0 * lv.x + x1 * lv.y + x2 * lv.z + x3 * lv.w;
    }
#pragma unroll
    for (int r = 0; r < R_LORA; ++r) {
        float v = acc[r];
#pragma unroll
        for (int off = 32; off > 0; off >>= 1) v += __shfl_down(v, off, 64);
        acc[r] = v;
    }
    __shared__ float red[R_LORA][4];
    int lane = tid & 63, wid = tid >> 6;
    if (lane == 0) {
#pragma unroll
        for (int r = 0; r < R_LORA; ++r) red[r][wid] = acc[r];
    }
    __syncthreads();
    if (tid < 32) {
        float v = 0.0f;
        if (tid < R_LORA) v = red[tid][0] + red[tid][1] + red[tid][2] + red[tid][3];
        else if (tid == R_LORA) v = 1.0f;
        Xg[(size_t)n * KAUG + 1024 + tid] = f2bf(v);
    }
}

// ---------------------------------------------------------------------------
// Fused weight augment for all four projections. grid (E_DIM, 4): q,k,v,o.
// ---------------------------------------------------------------------------
__global__ __launch_bounds__(256) void aug_w4_kernel(
    const float* __restrict__ Wq, const float* __restrict__ lbq, const float* __restrict__ bq,
    const float* __restrict__ Wk, const float* __restrict__ lbk, const float* __restrict__ bk_,
    const float* __restrict__ Wv, const float* __restrict__ lbv, const float* __restrict__ bv_,
    const float* __restrict__ Wo, const float* __restrict__ lbo, const float* __restrict__ bo,
    USH* __restrict__ Wg_base) {
    int e = blockIdx.x, y = blockIdx.y, tid = threadIdx.x;
    const float* W    = (y == 0) ? Wq : (y == 1) ? Wk : (y == 2) ? Wv : Wo;
    const float* lb   = (y == 0) ? lbq : (y == 1) ? lbk : (y == 2) ? lbv : lbo;
    const float* bias = (y == 0) ? bq : (y == 1) ? bk_ : (y == 2) ? bv_ : bo;
    USH* Wg = Wg_base + (size_t)y * WG_N;

    float4 v = *(const float4*)(W + (size_t)e * E_DIM + tid * 4);
    ushort4 o;
    o.x = f2bf(v.x); o.y = f2bf(v.y); o.z = f2bf(v.z); o.w = f2bf(v.w);
    *(ushort4*)(Wg + (size_t)e * KAUG + tid * 4) = o;
    if (tid < 32) {
        float t = (tid < R_LORA) ? lb[(size_t)e * R_LORA + tid]
                                 : (tid == R_LORA ? bias[e] : 0.0f);
        Wg[(size_t)e * KAUG + 1024 + tid] = f2bf(t);
    }
}

// ---------------------------------------------------------------------------
// Batched q/k/v GEMM, 128x128 tile, grid (8, 32, 3) = 768. Double-buffered
// LDS + prefetch-before-compute + ONE barrier per K-step.
// ---------------------------------------------------------------------------
__global__ __launch_bounds__(256) void gemm_qkv_kernel(
    const USH* __restrict__ Xg_base, const USH* __restrict__ Wg_base,
    USH* __restrict__ qkv_base) {
    __shared__ __align__(16) USH As[2][128 * 32];
    __shared__ __align__(16) USH Bs[2][128 * 32];

    int orig = blockIdx.x + (blockIdx.y << 3) + blockIdx.z * 256;   // grid 8x32x3
    int v_ = (orig & 7) * 96 + (orig >> 3);                          // bijective, 768%8==0
    int e0 = (v_ & 7) * 128, n0 = ((v_ >> 3) & 31) * 128, z = v_ >> 8;

    const USH* Xg = Xg_base + (size_t)z * XG_N;
    const USH* Wg = Wg_base + (size_t)z * WG_N;
    USH* out = qkv_base + (size_t)z * HSZ;
    float scale = (z == 0) ? Q_SCALE : 1.0f;

    int tid = threadIdx.x;
    int wid = tid >> 6, lane = tid & 63, quad = lane >> 4, l16 = lane & 15;
    int wm = wid & 1, wn = wid >> 1;

    int r0 = wid * 16 + (lane >> 2);
    int k8 = (lane & 3) * 8;

    f32x4 acc[4][4];
    const f32x4 fzero = {0.f, 0.f, 0.f, 0.f};
#pragma unroll
    for (int i = 0; i < 4; ++i)
#pragma unroll
        for (int j = 0; j < 4; ++j) acc[i][j] = fzero;

    // prologue: stage kt=0 into buf 0
    async_cp16(Xg + (size_t)(n0 + r0) * KAUG + k8,       As[0] + (wid * 16) * 32);
    async_cp16(Xg + (size_t)(n0 + 64 + r0) * KAUG + k8,  As[0] + (64 + wid * 16) * 32);
    async_cp16(Wg + (size_t)(e0 + r0) * KAUG + k8,       Bs[0] + (wid * 16) * 32);
    async_cp16(Wg + (size_t)(e0 + 64 + r0) * KAUG + k8,  Bs[0] + (64 + wid * 16) * 32);
    __syncthreads();

    int cur = 0;
    for (int kt = 0; kt < KAUG; kt += 32, cur ^= 1) {
        if (kt + 32 < KAUG) {
            int kn = kt + 32;
            async_cp16(Xg + (size_t)(n0 + r0) * KAUG + kn + k8,       As[cur ^ 1] + (wid * 16) * 32);
            async_cp16(Xg + (size_t)(n0 + 64 + r0) * KAUG + kn + k8,  As[cur ^ 1] + (64 + wid * 16) * 32);
            async_cp16(Wg + (size_t)(e0 + r0) * KAUG + kn + k8,       Bs[cur ^ 1] + (wid * 16) * 32);
            async_cp16(Wg + (size_t)(e0 + 64 + r0) * KAUG + kn + k8,  Bs[cur ^ 1] + (64 + wid * 16) * 32);
        }

        bf16x8 af[4], bfr[4];
#pragma unroll
        for (int i = 0; i < 4; ++i)
            af[i] = *(const bf16x8*)&As[cur][(wm * 64 + i * 16 + l16) * 32 + quad * 8];
#pragma unroll
        for (int j = 0; j < 4; ++j)
            bfr[j] = *(const bf16x8*)&Bs[cur][(wn * 64 + j * 16 + l16) * 32 + quad * 8];
#pragma unroll
        for (int i = 0; i < 4; ++i)
#pragma unroll
            for (int j = 0; j < 4; ++j)
                acc[i][j] = __builtin_amdgcn_mfma_f32_16x16x32_bf16(
                    af[i], bfr[j], acc[i][j], 0, 0, 0);

        // one barrier: drains prefetch (landed under compute) + releases cur
        __syncthreads();
    }

#pragma unroll
    for (int i = 0; i < 4; ++i) {
#pragma unroll
        for (int j = 0; j < 4; ++j) {
#pragma unroll
            for (int r = 0; r < 4; ++r) {
                int nr = n0 + wm * 64 + i * 16 + quad * 4 + r;
                int ec = e0 + wn * 64 + j * 16 + l16;
                float v = acc[i][j][r] * scale;
                int b = nr & 1, h = ec >> 6, d = ec & 63;
                if (z != 2) {
                    int t = nr >> 1;
                    out[(((size_t)(b * 16 + h) * T_LEN + t) << 6) + d] = f2bf(v);
                } else {
                    int s = nr >> 1;
                    out[(((size_t)(b * 16 + h) * HD + d) << 11) + s] = f2bf(v);
                }
            }
        }
    }
}

// ---------------------------------------------------------------------------
// O-projection GEMM -> fp32 d_out. grid (8, 64) = 512 blocks. Pipelined
// single-barrier loop (dbuf LDS: 2x(4+8) = 24 KB).
// ---------------------------------------------------------------------------
__global__ __launch_bounds__(256) void gemm_o_kernel(
    const USH* __restrict__ Xg, const USH* __restrict__ Wg,
    float* __restrict__ out) {
    __shared__ __align__(16) USH As[2][64 * 32];
    __shared__ __align__(16) USH Bs[2][128 * 32];

    int orig = blockIdx.x + (blockIdx.y << 3);          // grid 8x64
    int v_ = ((orig & 7) << 6) + (orig >> 3);           // 64 blocks/XCD
    int e0 = (v_ & 7) * 128, n0 = (v_ >> 3) * 64;

    int tid = threadIdx.x;
    int wid = tid >> 6, lane = tid & 63, quad = lane >> 4, l16 = lane & 15;
    int wm = wid & 1, wn = wid >> 1;
    int r0 = wid * 16 + (lane >> 2);
    int k8 = (lane & 3) * 8;

    f32x4 acc[2][4];
    const f32x4 fzero = {0.f, 0.f, 0.f, 0.f};
#pragma unroll
    for (int i = 0; i < 2; ++i)
#pragma unroll
        for (int j = 0; j < 4; ++j) acc[i][j] = fzero;

    // prologue: stage kt=0 into buf 0
    async_cp16(Xg + (size_t)(n0 + r0) * KAUG + k8,       As[0] + (wid * 16) * 32);
    async_cp16(Wg + (size_t)(e0 + r0) * KAUG + k8,       Bs[0] + (wid * 16) * 32);
    async_cp16(Wg + (size_t)(e0 + 64 + r0) * KAUG + k8,  Bs[0] + (64 + wid * 16) * 32);
    __syncthreads();

    int cur = 0;
    for (int kt = 0; kt < KAUG; kt += 32, cur ^= 1) {
        if (kt + 32 < KAUG) {
            int kn = kt + 32;
            async_cp16(Xg + (size_t)(n0 + r0) * KAUG + kn + k8,       As[cur ^ 1] + (wid * 16) * 32);
            async_cp16(Wg + (size_t)(e0 + r0) * KAUG + kn + k8,       Bs[cur ^ 1] + (wid * 16) * 32);
            async_cp16(Wg + (size_t)(e0 + 64 + r0) * KAUG + kn + k8,  Bs[cur ^ 1] + (64 + wid * 16) * 32);
        }

        bf16x8 af[2], bfr[4];
#pragma unroll
        for (int i = 0; i < 2; ++i)
            af[i] = *(const bf16x8*)&As[cur][(wm * 32 + i * 16 + l16) * 32 + quad * 8];
#pragma unroll
        for (int j = 0; j < 4; ++j)
            bfr[j] = *(const bf16x8*)&Bs[cur][(wn * 64 + j * 16 + l16) * 32 + quad * 8];
#pragma unroll
        for (int i = 0; i < 2; ++i)
#pragma unroll
            for (int j = 0; j < 4; ++j)
                acc[i][j] = __builtin_amdgcn_mfma_f32_16x16x32_bf16(
                    af[i], bfr[j], acc[i][j], 0, 0, 0);

        __syncthreads();
    }

#pragma unroll
    for (int i = 0; i < 2; ++i)
#pragma unroll
        for (int j = 0; j < 4; ++j)
#pragma unroll
            for (int r = 0; r < 4; ++r) {
                int nr = n0 + wm * 32 + i * 16 + quad * 4 + r;
                int ec = e0 + wn * 64 + j * 16 + l16;
                out[(size_t)nr * E_DIM + ec] = acc[i][j][r];
            }
}

// ---------------------------------------------------------------------------
// Flash v13: 32x32 MFMA + fully in-register softmax (m214/T12 structure).
// 4 waves x 32 t-rows = 128 t/block, grid (T/128, B*H) = 512 blocks.
// Swapped QK^T (A=K, B=Q) with mfma_32x32x16: C col=lane&31=t -> each lane
// owns ONE t-row with 32 P-values in regs. exp2 + lsum in-lane (+1 shfl_xor).
// P -> PV A-operand via pack_bf + permlane32_swap (T12): NO P LDS round-trip.
// K/V staged via global_load_lds in FRAGMENT-MAJOR layout (lane reads the
// exact 16B slot it staged -> zero bank conflicts by construction).
// K/V double-buffered, prefetch-before-compute, one barrier/iter, XCD chunk
// (4 heads/XCD, K/V L2-resident). LDS 32 KB. 2 waves/SIMD, ~160 VGPR.
// ---------------------------------------------------------------------------
__global__ __launch_bounds__(256, 2) void flash_mfma_kernel(
    const USH* __restrict__ qp, const USH* __restrict__ kp,
    const USH* __restrict__ vpt, USH* __restrict__ ohg,
    float* __restrict__ lbuf) {
    __shared__ __align__(16) USH Ks[2][4096];   // 8 frags x 512 USH (1KB each)
    __shared__ __align__(16) USH Vs[2][4096];

    int orig = blockIdx.x + (blockIdx.y << 4);  // grid 16x32
    int v_ = ((orig & 7) << 6) + (orig >> 3);   // 64 blocks/XCD chunk
    int t0 = (v_ & 15) * 128, bh = v_ >> 4;     // chunk c -> heads [4c, 4c+4)

    int tid = threadIdx.x, w = tid >> 6, lane = tid & 63;
    int lo = lane & 31, hi = lane >> 5;
    size_t headO = (size_t)bh * (T_LEN * HD);
    int t_base = t0 + w * 32;

    // Q fragments direct from global (B-operand: n=t=lo, k=kb*16+hi*8+e)
    bf16x8 bq[4];
    {
        const USH* qrow = qp + headO + (size_t)(t_base + lo) * HD + hi * 8;
#pragma unroll
        for (int kb = 0; kb < 4; ++kb)
            bq[kb] = *(const bf16x8*)(qrow + kb * 16);
    }

    // prologue: stage K[0], V[0]. Frag f: K rows (f>>2)*32+lo, k (f&3)*16+hi*8
    //           V frag g: d (g>>2)*32+lo, s (g&3)*16+hi*8. Wave w -> f=2w,2w+1.
#pragma unroll
    for (int c = 0; c < 2; ++c) {
        int f = w * 2 + c;
        async_cp16(kp + headO + (size_t)((f >> 2) * 32 + lo) * HD + (f & 3) * 16 + hi * 8,
                   &Ks[0][f * 512]);
        async_cp16(vpt + headO + (size_t)((f >> 2) * 32 + lo) * S_LEN + (f & 3) * 16 + hi * 8,
                   &Vs[0][f * 512]);
    }
    __syncthreads();

    const f32x16 z16 = {0,0,0,0,0,0,0,0,0,0,0,0,0,0,0,0};
    f32x16 o0 = z16, o1 = z16;
    float lsum = 0.f;

    for (int it = 0; it < S_LEN / 64; ++it) {
        int cur = it & 1;
        // prefetch next tile (K and V) into the other buffer
        if (it + 1 < S_LEN / 64) {
            int sn = (it + 1) * 64;
#pragma unroll
            for (int c = 0; c < 2; ++c) {
                int f = w * 2 + c;
                async_cp16(kp + headO + (size_t)(sn + (f >> 2) * 32 + lo) * HD + (f & 3) * 16 + hi * 8,
                           &Ks[cur ^ 1][f * 512]);
                async_cp16(vpt + headO + (size_t)((f >> 2) * 32 + lo) * S_LEN + sn + (f & 3) * 16 + hi * 8,
                           &Vs[cur ^ 1][f * 512]);
            }
        }

        // QK^T swapped: sc[st] = 32x32 tile, C[row=s_local][col=t_local=lo]
        // sc[st][reg] = score(t = t_base+lo, s = it*64 + st*32 + (reg&3)+8*(reg>>2)+4*hi)
        f32x16 sc0 = z16, sc1 = z16;
        __builtin_amdgcn_s_setprio(1);
#pragma unroll
        for (int kb = 0; kb < 4; ++kb) {
            bf16x8 ak0 = *(const bf16x8*)&Ks[cur][(0 * 4 + kb) * 512 + lane * 8];
            sc0 = __builtin_amdgcn_mfma_f32_32x32x16_bf16(ak0, bq[kb], sc0, 0, 0, 0);
        }
#pragma unroll
        for (int kb = 0; kb < 4; ++kb) {
            bf16x8 ak1 = *(const bf16x8*)&Ks[cur][(1 * 4 + kb) * 512 + lane * 8];
            sc1 = __builtin_amdgcn_mfma_f32_32x32x16_bf16(ak1, bq[kb], sc1, 0, 0, 0);
        }
        __builtin_amdgcn_s_setprio(0);

        // softmax (fixed m=0): exp2 in place, 4 partial sums
        float ls0 = 0.f, ls1 = 0.f, ls2 = 0.f, ls3 = 0.f;
#pragma unroll
        for (int r = 0; r < 16; ++r) {
            float p0 = __builtin_amdgcn_exp2f(sc0[r]);
            float p1 = __builtin_amdgcn_exp2f(sc1[r]);
            sc0[r] = p0; sc1[r] = p1;
            if ((r & 3) == 0)      { ls0 += p0; ls0 += p1; }
            else if ((r & 3) == 1) { ls1 += p0; ls1 += p1; }
            else if ((r & 3) == 2) { ls2 += p0; ls2 += p1; }
            else                   { ls3 += p0; ls3 += p1; }
        }
        lsum += (ls0 + ls1) + (ls2 + ls3);

        // P -> PV A-frags in registers (T12): per k-step ks = st*2+hh,
        // A-frag k = s_in_step = hi*8+e. dwords: swap(pk(q0,q1), pk(q4,q5))
        // -> {dword0, dword2}; swap(pk(q2,q3), pk(q6,q7)) -> {dword1, dword3}.
        bf16x8 pa[4];
#pragma unroll
        for (int st = 0; st < 2; ++st) {
#pragma unroll
            for (int hh = 0; hh < 2; ++hh) {
                const f32x16& s_ = st ? sc1 : sc0;
                uint32_t a0 = pack_bf_trunc(s_[hh * 8 + 0], s_[hh * 8 + 1]);
                uint32_t a1 = pack_bf_trunc(s_[hh * 8 + 2], s_[hh * 8 + 3]);
                uint32_t a2 = pack_bf_trunc(s_[hh * 8 + 4], s_[hh * 8 + 5]);
                uint32_t a3 = pack_bf_trunc(s_[hh * 8 + 6], s_[hh * 8 + 7]);
                u32x2 r02 = __builtin_amdgcn_permlane32_swap(a0, a2, false, false);
                u32x2 r13 = __builtin_amdgcn_permlane32_swap(a1, a3, false, false);
                u32x4 pd = {r02[0], r13[0], r02[1], r13[1]};
                pa[st * 2 + hh] = __builtin_bit_cast(bf16x8, pd);
            }
        }

        // PV: o[dt] (C rows = t, cols = d = dt*32+lo), k-steps over s
        __builtin_amdgcn_s_setprio(1);
#pragma unroll
        for (int ks = 0; ks < 4; ++ks) {
            bf16x8 bv0 = *(const bf16x8*)&Vs[cur][(0 * 4 + ks) * 512 + lane * 8];
            o0 = __builtin_amdgcn_mfma_f32_32x32x16_bf16(pa[ks], bv0, o0, 0, 0, 0);
        }
#pragma unroll
        for (int ks = 0; ks < 4; ++ks) {
            bf16x8 bv1 = *(const bf16x8*)&Vs[cur][(1 * 4 + ks) * 512 + lane * 8];
            o1 = __builtin_amdgcn_mfma_f32_32x32x16_bf16(pa[ks], bv1, o1, 0, 0, 0);
        }
        __builtin_amdgcn_s_setprio(0);

        // one barrier/iter: drains prefetch + releases cur buffers
        __syncthreads();
    }

    // lane owns full row t = t_base + lo split with partner: combine halves
    lsum += __shfl_xor(lsum, 32, 64);
    float rinv = 1.0f / lsum;

    int b = bh >> 4, h = bh & 15;
    float inv[16];
#pragma unroll
    for (int r = 0; r < 16; ++r) {
        int rr = (r & 3) + 8 * (r >> 2) + 4 * hi;    // t-local of o[*][r]
        inv[r] = __shfl(rinv, rr, 64);               // lane rr holds that t
    }
#pragma unroll
    for (int r = 0; r < 16; ++r) {
        int t = t_base + (r & 3) + 8 * (r >> 2) + 4 * hi;
        size_t nrow = (size_t)(t * 2 + b) * KAUG + h * 64;
        ohg[nrow + lo]      = f2bf(o0[r] * inv[r]);
        ohg[nrow + 32 + lo] = f2bf(o1[r] * inv[r]);
    }
    if (lane < 32)
        lbuf[(size_t)bh * T_LEN + t_base + lane] = rinv;   // store 1/lsum
}

// ---------------------------------------------------------------------------
// attnw v6: 128t x 64s per block, grid = 1024 blocks. Q direct, K dbuf with
// next-head prefetch, one barrier/head, XCD-chunked swizzle, native exp2,
// lbuf holds 1/lsum (no rcp chain). No per-MFMA setprio (m190).
// ---------------------------------------------------------------------------
__global__ __launch_bounds__(256, 4) void attnw_mfma_kernel(
    const USH* __restrict__ qp, const USH* __restrict__ kp,
    const float* __restrict__ lbuf, float* __restrict__ aw) {
    __shared__ __align__(16) USH Ks[2][4096];

    int orig = blockIdx.x + (blockIdx.y << 5) + (blockIdx.z << 9);  // grid 32x16x2
    int v_ = ((orig & 7) << 7) + (orig >> 3);                       // 128 blocks/XCD
    int s0 = (v_ & 31) * 64, t0 = ((v_ >> 5) & 15) * 128, b = v_ >> 9;

    int tid = threadIdx.x, w = tid >> 6, lane = tid & 63;
    int quad = lane >> 4, l16 = lane & 15;

    const f32x4 fzero = {0.f, 0.f, 0.f, 0.f};
    f32x4 acc[2][4];
#pragma unroll
    for (int i2 = 0; i2 < 2; ++i2)
#pragma unroll
        for (int j = 0; j < 4; ++j) acc[i2][j] = fzero;

    // prologue: stage K for head 0
    {
        size_t head0 = (size_t)(b * 16) * (T_LEN * HD);
#pragma unroll
        for (int half = 0; half < 2; ++half)
            async_cp16(kp + head0 + (size_t)(s0 + w * 16 + l16) * HD + half * 32 + quad * 8,
                       &Ks[0][w * 1024 + half * 512]);
    }
    __syncthreads();

    for (int h = 0; h < N_HEADS; ++h) {
        int bh = b * 16 + h;
        size_t head = (size_t)bh * (T_LEN * HD);
        int cur = h & 1;

        // prefetch next head's K into the other buffer
        if (h + 1 < N_HEADS) {
            size_t headn = head + (size_t)(T_LEN * HD);
#pragma unroll
            for (int half = 0; half < 2; ++half)
                async_cp16(kp + headn + (size_t)(s0 + w * 16 + l16) * HD + half * 32 + quad * 8,
                           &Ks[cur ^ 1][w * 1024 + half * 512]);
        }

        // Q fragments direct from global (A-operand; rows are wave-private)
        bf16x8 aq[2][2];
#pragma unroll
        for (int i2 = 0; i2 < 2; ++i2) {
            int i = w * 2 + i2;
            const USH* qrow = qp + head + (size_t)(t0 + i * 16 + l16) * HD + quad * 8;
            aq[i2][0] = *(const bf16x8*)qrow;
            aq[i2][1] = *(const bf16x8*)(qrow + 32);
        }

        float il[2][4];
#pragma unroll
        for (int i2 = 0; i2 < 2; ++i2)
#pragma unroll
            for (int r = 0; r < 4; ++r) {
                int t = t0 + w * 32 + i2 * 16 + quad * 4 + r;
                il[i2][r] = lbuf[(size_t)bh * T_LEN + t];   // already 1/lsum
            }

        bf16x8 bk[4][2];
#pragma unroll
        for (int j = 0; j < 4; ++j)
#pragma unroll
            for (int half = 0; half < 2; ++half)
                bk[j][half] = *(const bf16x8*)&Ks[cur][j * 1024 + half * 512 + quad * 128 + l16 * 8];

#pragma unroll
        for (int i2 = 0; i2 < 2; ++i2) {
#pragma unroll
            for (int j = 0; j < 4; ++j) {
                f32x4 s = __builtin_amdgcn_mfma_f32_16x16x32_bf16(aq[i2][0], bk[j][0], fzero, 0, 0, 0);
                s = __builtin_amdgcn_mfma_f32_16x16x32_bf16(aq[i2][1], bk[j][1], s, 0, 0, 0);
#pragma unroll
                for (int r = 0; r < 4; ++r)
                    acc[i2][j][r] += __builtin_amdgcn_exp2f(s[r]) * il[i2][r];
            }
        }

        // single barrier: drains this head's prefetch + releases cur buffer
        __syncthreads();
    }

    const float inv_h = 1.0f / (float)N_HEADS;
#pragma unroll
    for (int i2 = 0; i2 < 2; ++i2)
#pragma unroll
        for (int j = 0; j < 4; ++j)
#pragma unroll
            for (int r = 0; r < 4; ++r) {
                int t = t0 + w * 32 + i2 * 16 + quad * 4 + r;
                aw[(size_t)b * T_LEN * S_LEN + (size_t)t * S_LEN + s0 + j * 16 + l16] =
                    acc[i2][j][r] * inv_h;
            }
}

// ---------------------------------------------------------------------------
extern "C" void kernel_launch(void* const* d_in, const int* in_sizes, int n_in,
                              void* d_out, int out_size, void* d_ws, size_t ws_size,
                              hipStream_t stream) {
    (void)in_sizes; (void)n_in; (void)out_size; (void)ws_size;

    const float* query = (const float*)d_in[0];
    const float* key_  = (const float*)d_in[1];
    const float* value = (const float*)d_in[2];
    const float* q_w = (const float*)d_in[3],  *q_b = (const float*)d_in[4];
    const float* q_la = (const float*)d_in[5], *q_lb = (const float*)d_in[6];
    const float* k_w = (const float*)d_in[7],  *k_b = (const float*)d_in[8];
    const float* k_la = (const float*)d_in[9], *k_lb = (const float*)d_in[10];
    const float* v_w = (const float*)d_in[11], *v_b = (const float*)d_in[12];
    const float* v_la = (const float*)d_in[13], *v_lb = (const float*)d_in[14];
    const float* o_w = (const float*)d_in[15], *o_b = (const float*)d_in[16];
    const float* o_la = (const float*)d_in[17], *o_lb = (const float*)d_in[18];

    USH* Xg   = (USH*)d_ws;                 // 3 * NROW*KAUG
    USH* Wg   = Xg + 3 * XG_N;              // 4 * E_DIM*KAUG
    USH* qkv  = Wg + 4 * WG_N;              // 3 * HSZ
    USH* qp   = qkv;
    USH* kp   = qkv + HSZ;
    USH* vpt  = qkv + 2 * HSZ;
    float* lbuf = (float*)(qkv + 3 * HSZ);

    float* out = (float*)d_out;                       // (T,B,E) fp32
    float* aw  = out + (size_t)T_LEN * B_SZ * E_DIM;  // (B,T,S) fp32

    dim3 blk(256);

    lora_aug_x3_kernel<<<dim3(NROW, 3), blk, 0, stream>>>(
        query, key_, value, q_la, k_la, v_la, Xg);
    aug_w4_kernel<<<dim3(E_DIM, 4), blk, 0, stream>>>(
        q_w, q_lb, q_b, k_w, k_lb, k_b, v_w, v_lb, v_b, o_w, o_lb, o_b, Wg);
    gemm_qkv_kernel<<<dim3(E_DIM / 128, NROW / 128, 3), blk, 0, stream>>>(Xg, Wg, qkv);

    flash_mfma_kernel<<<dim3(T_LEN / 128, B_SZ * N_HEADS), blk, 0, stream>>>(
        qp, kp, vpt, Xg, lbuf);
    attnw_mfma_kernel<<<dim3(S_LEN / 64, T_LEN / 128, B_SZ), blk, 0, stream>>>(
        qp, kp, lbuf, aw);

    lora_a_bf16_kernel<<<NROW, blk, 0, stream>>>(Xg, o_la);
    gemm_o_kernel<<<dim3(E_DIM / 128, NROW / 64), blk, 0, stream>>>(
        Xg, Wg + 3 * WG_N, out);
}

// Round 8
// 330.189 us; speedup vs baseline: 1.4318x; 1.1425x over previous
//
#include <hip/hip_runtime.h>
#include <stdint.h>

// Problem constants
#define E_DIM 1024
#define KAUG 1056            // 1024 + 16 (LoRA) + 1 (bias) + 15 pad
#define N_HEADS 16
#define HD 64
#define R_LORA 16
#define T_LEN 2048
#define B_SZ 2
#define S_LEN 2048
#define NROW 4096            // T*B == S*B
// q pre-scale: (1/sqrt(64)) * log2(e)  -> softmax becomes exp2(score)
#define Q_SCALE 0.1803368801111204f

#define XG_N ((size_t)NROW * KAUG)
#define WG_N ((size_t)E_DIM * KAUG)
#define HSZ  ((size_t)B_SZ * N_HEADS * T_LEN * HD)

typedef unsigned short USH;
typedef __bf16 bf16x8 __attribute__((ext_vector_type(8)));
typedef unsigned short ushort8 __attribute__((ext_vector_type(8)));
typedef float  f32x4  __attribute__((ext_vector_type(4)));
typedef float  f32x16 __attribute__((ext_vector_type(16)));
typedef unsigned int u32x2 __attribute__((ext_vector_type(2)));
typedef unsigned int u32x4 __attribute__((ext_vector_type(4)));

__device__ __forceinline__ USH f2bf(float f) {
    uint32_t u = __builtin_bit_cast(uint32_t, f);
    return (USH)((u + 0x7FFFu + ((u >> 16) & 1u)) >> 16);
}
__device__ __forceinline__ float bf2f(USH s) {
    uint32_t u = ((uint32_t)s) << 16;
    return __builtin_bit_cast(float, u);
}
__device__ __forceinline__ void async_cp16(const void* g, void* l) {
    __builtin_amdgcn_global_load_lds(
        (const __attribute__((address_space(1))) void*)g,
        (__attribute__((address_space(3))) void*)l, 16, 0, 0);
}
// pack hi16(x), hi16(y) -> dword (bf16 truncation; y in high half)
__device__ __forceinline__ uint32_t pack_bf_trunc(float x, float y) {
    return __builtin_amdgcn_perm(__builtin_bit_cast(uint32_t, y),
                                 __builtin_bit_cast(uint32_t, x), 0x07060302u);
}
// 8 floats -> bf16x8 with RNE rounding (matches f2bf store path)
__device__ __forceinline__ bf16x8 cvt8(float4 a, float4 b) {
    ushort8 u;
    u[0] = f2bf(a.x); u[1] = f2bf(a.y); u[2] = f2bf(a.z); u[3] = f2bf(a.w);
    u[4] = f2bf(b.x); u[5] = f2bf(b.y); u[6] = f2bf(b.z); u[7] = f2bf(b.w);
    return __builtin_bit_cast(bf16x8, u);
}

// ---------------------------------------------------------------------------
// lora_aug v2: MFMA-based. Block = 16 rows, 4 waves K-split (256 k each).
// A-frag = bf16(X row) (also stored to Xg -- cast-write is free);
// B-frag = bf16(la row). 8 x mfma_16x16x32 per wave -> XA[16][16] tile,
// combined across waves via one padded-LDS reduce. grid (NROW/16, 3) = 768.
// Replaces the 1-block-per-row / 16x butterfly-reduce structure (63 us,
// 768 MB of la L2 re-reads -> 16x less la traffic, zero shuffle chains).
// ---------------------------------------------------------------------------
__global__ __launch_bounds__(256) void lora_aug_x3_kernel(
    const float* __restrict__ Xq, const float* __restrict__ Xk,
    const float* __restrict__ Xv,
    const float* __restrict__ laq, const float* __restrict__ lak,
    const float* __restrict__ lav, USH* __restrict__ Xg_base) {
    int n0 = blockIdx.x * 16, y = blockIdx.y, tid = threadIdx.x;
    const float* X  = (y == 0) ? Xq : (y == 1) ? Xk : Xv;
    const float* la = (y == 0) ? laq : (y == 1) ? lak : lav;
    USH* Xg = Xg_base + (size_t)y * XG_N;

    int w = tid >> 6, lane = tid & 63, quad = lane >> 4, l16 = lane & 15;

    const float* xrow = X + (size_t)(n0 + l16) * E_DIM;
    const float* lrow = la + (size_t)l16 * E_DIM;
    USH* grow = Xg + (size_t)(n0 + l16) * KAUG;

    const f32x4 fzero = {0.f, 0.f, 0.f, 0.f};
    f32x4 acc = fzero;

#pragma unroll
    for (int i = 0; i < 8; ++i) {
        int k = w * 256 + i * 32 + quad * 8;
        bf16x8 af = cvt8(*(const float4*)(xrow + k), *(const float4*)(xrow + k + 4));
        *(bf16x8*)(grow + k) = af;                       // bf16 cast-write
        bf16x8 bf_ = cvt8(*(const float4*)(lrow + k), *(const float4*)(lrow + k + 4));
        acc = __builtin_amdgcn_mfma_f32_16x16x32_bf16(af, bf_, acc, 0, 0, 0);
    }

    // combine 4 wave-partials: acc[r] = XA[row = quad*4+r][col = l16] partial
    __shared__ float red[4][16][17];
#pragma unroll
    for (int r = 0; r < 4; ++r) red[w][quad * 4 + r][l16] = acc[r];
    __syncthreads();

    int row = tid >> 4, col = tid & 15;
    float v = red[0][row][col] + red[1][row][col] + red[2][row][col] + red[3][row][col];
    USH* trow = Xg + (size_t)(n0 + row) * KAUG + 1024;
    trow[col] = f2bf(v);                                 // XA cols 1024..1039
    trow[16 + col] = (col == 0) ? f2bf(1.0f) : (USH)0;   // bias col 1040, pad 0
}

// ---------------------------------------------------------------------------
// lora_a v2 (O-input tails): same MFMA structure; A-frags load bf16 Xg rows
// directly (already cast by flash). grid (NROW/16) = 256 blocks.
// ---------------------------------------------------------------------------
__global__ __launch_bounds__(256) void lora_a_bf16_kernel(
    USH* __restrict__ Xg, const float* __restrict__ la) {
    int n0 = blockIdx.x * 16, tid = threadIdx.x;
    int w = tid >> 6, lane = tid & 63, quad = lane >> 4, l16 = lane & 15;

    const USH* grow = Xg + (size_t)(n0 + l16) * KAUG;
    const float* lrow = la + (size_t)l16 * E_DIM;

    const f32x4 fzero = {0.f, 0.f, 0.f, 0.f};
    f32x4 acc = fzero;

#pragma unroll
    for (int i = 0; i < 8; ++i) {
        int k = w * 256 + i * 32 + quad * 8;
        bf16x8 af = *(const bf16x8*)(grow + k);
        bf16x8 bf_ = cvt8(*(const float4*)(lrow + k), *(const float4*)(lrow + k + 4));
        acc = __builtin_amdgcn_mfma_f32_16x16x32_bf16(af, bf_, acc, 0, 0, 0);
    }

    __shared__ float red[4][16][17];
#pragma unroll
    for (int r = 0; r < 4; ++r) red[w][quad * 4 + r][l16] = acc[r];
    __syncthreads();

    int row = tid >> 4, col = tid & 15;
    float v = red[0][row][col] + red[1][row][col] + red[2][row][col] + red[3][row][col];
    USH* trow = Xg + (size_t)(n0 + row) * KAUG + 1024;
    trow[col] = f2bf(v);
    trow[16 + col] = (col == 0) ? f2bf(1.0f) : (USH)0;
}

// ---------------------------------------------------------------------------
// Fused weight augment for all four projections. grid (E_DIM, 4): q,k,v,o.
// ---------------------------------------------------------------------------
__global__ __launch_bounds__(256) void aug_w4_kernel(
    const float* __restrict__ Wq, const float* __restrict__ lbq, const float* __restrict__ bq,
    const float* __restrict__ Wk, const float* __restrict__ lbk, const float* __restrict__ bk_,
    const float* __restrict__ Wv, const float* __restrict__ lbv, const float* __restrict__ bv_,
    const float* __restrict__ Wo, const float* __restrict__ lbo, const float* __restrict__ bo,
    USH* __restrict__ Wg_base) {
    int e = blockIdx.x, y = blockIdx.y, tid = threadIdx.x;
    const float* W    = (y == 0) ? Wq : (y == 1) ? Wk : (y == 2) ? Wv : Wo;
    const float* lb   = (y == 0) ? lbq : (y == 1) ? lbk : (y == 2) ? lbv : lbo;
    const float* bias = (y == 0) ? bq : (y == 1) ? bk_ : (y == 2) ? bv_ : bo;
    USH* Wg = Wg_base + (size_t)y * WG_N;

    float4 v = *(const float4*)(W + (size_t)e * E_DIM + tid * 4);
    ushort4 o;
    o.x = f2bf(v.x); o.y = f2bf(v.y); o.z = f2bf(v.z); o.w = f2bf(v.w);
    *(ushort4*)(Wg + (size_t)e * KAUG + tid * 4) = o;
    if (tid < 32) {
        float t = (tid < R_LORA) ? lb[(size_t)e * R_LORA + tid]
                                 : (tid == R_LORA ? bias[e] : 0.0f);
        Wg[(size_t)e * KAUG + 1024 + tid] = f2bf(t);
    }
}

// ---------------------------------------------------------------------------
// Batched q/k/v GEMM, 128x128 tile, grid (8, 32, 3) = 768. Double-buffered
// LDS + prefetch-before-compute + ONE barrier per K-step.
// ---------------------------------------------------------------------------
__global__ __launch_bounds__(256) void gemm_qkv_kernel(
    const USH* __restrict__ Xg_base, const USH* __restrict__ Wg_base,
    USH* __restrict__ qkv_base) {
    __shared__ __align__(16) USH As[2][128 * 32];
    __shared__ __align__(16) USH Bs[2][128 * 32];

    int orig = blockIdx.x + (blockIdx.y << 3) + blockIdx.z * 256;   // grid 8x32x3
    int v_ = (orig & 7) * 96 + (orig >> 3);                          // bijective, 768%8==0
    int e0 = (v_ & 7) * 128, n0 = ((v_ >> 3) & 31) * 128, z = v_ >> 8;

    const USH* Xg = Xg_base + (size_t)z * XG_N;
    const USH* Wg = Wg_base + (size_t)z * WG_N;
    USH* out = qkv_base + (size_t)z * HSZ;
    float scale = (z == 0) ? Q_SCALE : 1.0f;

    int tid = threadIdx.x;
    int wid = tid >> 6, lane = tid & 63, quad = lane >> 4, l16 = lane & 15;
    int wm = wid & 1, wn = wid >> 1;

    int r0 = wid * 16 + (lane >> 2);
    int k8 = (lane & 3) * 8;

    f32x4 acc[4][4];
    const f32x4 fzero = {0.f, 0.f, 0.f, 0.f};
#pragma unroll
    for (int i = 0; i < 4; ++i)
#pragma unroll
        for (int j = 0; j < 4; ++j) acc[i][j] = fzero;

    // prologue: stage kt=0 into buf 0
    async_cp16(Xg + (size_t)(n0 + r0) * KAUG + k8,       As[0] + (wid * 16) * 32);
    async_cp16(Xg + (size_t)(n0 + 64 + r0) * KAUG + k8,  As[0] + (64 + wid * 16) * 32);
    async_cp16(Wg + (size_t)(e0 + r0) * KAUG + k8,       Bs[0] + (wid * 16) * 32);
    async_cp16(Wg + (size_t)(e0 + 64 + r0) * KAUG + k8,  Bs[0] + (64 + wid * 16) * 32);
    __syncthreads();

    int cur = 0;
    for (int kt = 0; kt < KAUG; kt += 32, cur ^= 1) {
        if (kt + 32 < KAUG) {
            int kn = kt + 32;
            async_cp16(Xg + (size_t)(n0 + r0) * KAUG + kn + k8,       As[cur ^ 1] + (wid * 16) * 32);
            async_cp16(Xg + (size_t)(n0 + 64 + r0) * KAUG + kn + k8,  As[cur ^ 1] + (64 + wid * 16) * 32);
            async_cp16(Wg + (size_t)(e0 + r0) * KAUG + kn + k8,       Bs[cur ^ 1] + (wid * 16) * 32);
            async_cp16(Wg + (size_t)(e0 + 64 + r0) * KAUG + kn + k8,  Bs[cur ^ 1] + (64 + wid * 16) * 32);
        }

        bf16x8 af[4], bfr[4];
#pragma unroll
        for (int i = 0; i < 4; ++i)
            af[i] = *(const bf16x8*)&As[cur][(wm * 64 + i * 16 + l16) * 32 + quad * 8];
#pragma unroll
        for (int j = 0; j < 4; ++j)
            bfr[j] = *(const bf16x8*)&Bs[cur][(wn * 64 + j * 16 + l16) * 32 + quad * 8];
#pragma unroll
        for (int i = 0; i < 4; ++i)
#pragma unroll
            for (int j = 0; j < 4; ++j)
                acc[i][j] = __builtin_amdgcn_mfma_f32_16x16x32_bf16(
                    af[i], bfr[j], acc[i][j], 0, 0, 0);

        // one barrier: drains prefetch (landed under compute) + releases cur
        __syncthreads();
    }

#pragma unroll
    for (int i = 0; i < 4; ++i) {
#pragma unroll
        for (int j = 0; j < 4; ++j) {
#pragma unroll
            for (int r = 0; r < 4; ++r) {
                int nr = n0 + wm * 64 + i * 16 + quad * 4 + r;
                int ec = e0 + wn * 64 + j * 16 + l16;
                float v = acc[i][j][r] * scale;
                int b = nr & 1, h = ec >> 6, d = ec & 63;
                if (z != 2) {
                    int t = nr >> 1;
                    out[(((size_t)(b * 16 + h) * T_LEN + t) << 6) + d] = f2bf(v);
                } else {
                    int s = nr >> 1;
                    out[(((size_t)(b * 16 + h) * HD + d) << 11) + s] = f2bf(v);
                }
            }
        }
    }
}

// ---------------------------------------------------------------------------
// O-projection GEMM -> fp32 d_out. grid (8, 64) = 512 blocks. Pipelined
// single-barrier loop (dbuf LDS: 2x(4+8) = 24 KB).
// ---------------------------------------------------------------------------
__global__ __launch_bounds__(256) void gemm_o_kernel(
    const USH* __restrict__ Xg, const USH* __restrict__ Wg,
    float* __restrict__ out) {
    __shared__ __align__(16) USH As[2][64 * 32];
    __shared__ __align__(16) USH Bs[2][128 * 32];

    int orig = blockIdx.x + (blockIdx.y << 3);          // grid 8x64
    int v_ = ((orig & 7) << 6) + (orig >> 3);           // 64 blocks/XCD
    int e0 = (v_ & 7) * 128, n0 = (v_ >> 3) * 64;

    int tid = threadIdx.x;
    int wid = tid >> 6, lane = tid & 63, quad = lane >> 4, l16 = lane & 15;
    int wm = wid & 1, wn = wid >> 1;
    int r0 = wid * 16 + (lane >> 2);
    int k8 = (lane & 3) * 8;

    f32x4 acc[2][4];
    const f32x4 fzero = {0.f, 0.f, 0.f, 0.f};
#pragma unroll
    for (int i = 0; i < 2; ++i)
#pragma unroll
        for (int j = 0; j < 4; ++j) acc[i][j] = fzero;

    // prologue: stage kt=0 into buf 0
    async_cp16(Xg + (size_t)(n0 + r0) * KAUG + k8,       As[0] + (wid * 16) * 32);
    async_cp16(Wg + (size_t)(e0 + r0) * KAUG + k8,       Bs[0] + (wid * 16) * 32);
    async_cp16(Wg + (size_t)(e0 + 64 + r0) * KAUG + k8,  Bs[0] + (64 + wid * 16) * 32);
    __syncthreads();

    int cur = 0;
    for (int kt = 0; kt < KAUG; kt += 32, cur ^= 1) {
        if (kt + 32 < KAUG) {
            int kn = kt + 32;
            async_cp16(Xg + (size_t)(n0 + r0) * KAUG + kn + k8,       As[cur ^ 1] + (wid * 16) * 32);
            async_cp16(Wg + (size_t)(e0 + r0) * KAUG + kn + k8,       Bs[cur ^ 1] + (wid * 16) * 32);
            async_cp16(Wg + (size_t)(e0 + 64 + r0) * KAUG + kn + k8,  Bs[cur ^ 1] + (64 + wid * 16) * 32);
        }

        bf16x8 af[2], bfr[4];
#pragma unroll
        for (int i = 0; i < 2; ++i)
            af[i] = *(const bf16x8*)&As[cur][(wm * 32 + i * 16 + l16) * 32 + quad * 8];
#pragma unroll
        for (int j = 0; j < 4; ++j)
            bfr[j] = *(const bf16x8*)&Bs[cur][(wn * 64 + j * 16 + l16) * 32 + quad * 8];
#pragma unroll
        for (int i = 0; i < 2; ++i)
#pragma unroll
            for (int j = 0; j < 4; ++j)
                acc[i][j] = __builtin_amdgcn_mfma_f32_16x16x32_bf16(
                    af[i], bfr[j], acc[i][j], 0, 0, 0);

        __syncthreads();
    }

#pragma unroll
    for (int i = 0; i < 2; ++i)
#pragma unroll
        for (int j = 0; j < 4; ++j)
#pragma unroll
            for (int r = 0; r < 4; ++r) {
                int nr = n0 + wm * 32 + i * 16 + quad * 4 + r;
                int ec = e0 + wn * 64 + j * 16 + l16;
                out[(size_t)nr * E_DIM + ec] = acc[i][j][r];
            }
}

// ---------------------------------------------------------------------------
// Flash v13: 32x32 MFMA + fully in-register softmax (m214/T12 structure).
// 4 waves x 32 t-rows = 128 t/block, grid (T/128, B*H) = 512 blocks.
// Swapped QK^T (A=K, B=Q) with mfma_32x32x16: C col=lane&31=t -> each lane
// owns ONE t-row with 32 P-values in regs. exp2 + lsum in-lane (+1 shfl_xor).
// P -> PV A-operand via pack_bf + permlane32_swap (T12): NO P LDS round-trip.
// K/V staged via global_load_lds in FRAGMENT-MAJOR layout (lane reads the
// exact 16B slot it staged -> zero bank conflicts by construction).
// K/V double-buffered, prefetch-before-compute, one barrier/iter, XCD chunk
// (4 heads/XCD, K/V L2-resident). LDS 32 KB. 2 waves/SIMD, ~160 VGPR.
// ---------------------------------------------------------------------------
__global__ __launch_bounds__(256, 2) void flash_mfma_kernel(
    const USH* __restrict__ qp, const USH* __restrict__ kp,
    const USH* __restrict__ vpt, USH* __restrict__ ohg,
    float* __restrict__ lbuf) {
    __shared__ __align__(16) USH Ks[2][4096];   // 8 frags x 512 USH (1KB each)
    __shared__ __align__(16) USH Vs[2][4096];

    int orig = blockIdx.x + (blockIdx.y << 4);  // grid 16x32
    int v_ = ((orig & 7) << 6) + (orig >> 3);   // 64 blocks/XCD chunk
    int t0 = (v_ & 15) * 128, bh = v_ >> 4;     // chunk c -> heads [4c, 4c+4)

    int tid = threadIdx.x, w = tid >> 6, lane = tid & 63;
    int lo = lane & 31, hi = lane >> 5;
    size_t headO = (size_t)bh * (T_LEN * HD);
    int t_base = t0 + w * 32;

    // Q fragments direct from global (B-operand: n=t=lo, k=kb*16+hi*8+e)
    bf16x8 bq[4];
    {
        const USH* qrow = qp + headO + (size_t)(t_base + lo) * HD + hi * 8;
#pragma unroll
        for (int kb = 0; kb < 4; ++kb)
            bq[kb] = *(const bf16x8*)(qrow + kb * 16);
    }

    // prologue: stage K[0], V[0]. Frag f: K rows (f>>2)*32+lo, k (f&3)*16+hi*8
    //           V frag g: d (g>>2)*32+lo, s (g&3)*16+hi*8. Wave w -> f=2w,2w+1.
#pragma unroll
    for (int c = 0; c < 2; ++c) {
        int f = w * 2 + c;
        async_cp16(kp + headO + (size_t)((f >> 2) * 32 + lo) * HD + (f & 3) * 16 + hi * 8,
                   &Ks[0][f * 512]);
        async_cp16(vpt + headO + (size_t)((f >> 2) * 32 + lo) * S_LEN + (f & 3) * 16 + hi * 8,
                   &Vs[0][f * 512]);
    }
    __syncthreads();

    const f32x16 z16 = {0,0,0,0,0,0,0,0,0,0,0,0,0,0,0,0};
    f32x16 o0 = z16, o1 = z16;
    float lsum = 0.f;

    for (int it = 0; it < S_LEN / 64; ++it) {
        int cur = it & 1;
        // prefetch next tile (K and V) into the other buffer
        if (it + 1 < S_LEN / 64) {
            int sn = (it + 1) * 64;
#pragma unroll
            for (int c = 0; c < 2; ++c) {
                int f = w * 2 + c;
                async_cp16(kp + headO + (size_t)(sn + (f >> 2) * 32 + lo) * HD + (f & 3) * 16 + hi * 8,
                           &Ks[cur ^ 1][f * 512]);
                async_cp16(vpt + headO + (size_t)((f >> 2) * 32 + lo) * S_LEN + sn + (f & 3) * 16 + hi * 8,
                           &Vs[cur ^ 1][f * 512]);
            }
        }

        // QK^T swapped: sc[st] = 32x32 tile, C[row=s_local][col=t_local=lo]
        // sc[st][reg] = score(t = t_base+lo, s = it*64 + st*32 + (reg&3)+8*(reg>>2)+4*hi)
        f32x16 sc0 = z16, sc1 = z16;
        __builtin_amdgcn_s_setprio(1);
#pragma unroll
        for (int kb = 0; kb < 4; ++kb) {
            bf16x8 ak0 = *(const bf16x8*)&Ks[cur][(0 * 4 + kb) * 512 + lane * 8];
            sc0 = __builtin_amdgcn_mfma_f32_32x32x16_bf16(ak0, bq[kb], sc0, 0, 0, 0);
        }
#pragma unroll
        for (int kb = 0; kb < 4; ++kb) {
            bf16x8 ak1 = *(const bf16x8*)&Ks[cur][(1 * 4 + kb) * 512 + lane * 8];
            sc1 = __builtin_amdgcn_mfma_f32_32x32x16_bf16(ak1, bq[kb], sc1, 0, 0, 0);
        }
        __builtin_amdgcn_s_setprio(0);

        // softmax (fixed m=0): exp2 in place, 4 partial sums
        float ls0 = 0.f, ls1 = 0.f, ls2 = 0.f, ls3 = 0.f;
#pragma unroll
        for (int r = 0; r < 16; ++r) {
            float p0 = __builtin_amdgcn_exp2f(sc0[r]);
            float p1 = __builtin_amdgcn_exp2f(sc1[r]);
            sc0[r] = p0; sc1[r] = p1;
            if ((r & 3) == 0)      { ls0 += p0; ls0 += p1; }
            else if ((r & 3) == 1) { ls1 += p0; ls1 += p1; }
            else if ((r & 3) == 2) { ls2 += p0; ls2 += p1; }
            else                   { ls3 += p0; ls3 += p1; }
        }
        lsum += (ls0 + ls1) + (ls2 + ls3);

        // P -> PV A-frags in registers (T12): per k-step ks = st*2+hh,
        // A-frag k = s_in_step = hi*8+e. dwords: swap(pk(q0,q1), pk(q4,q5))
        // -> {dword0, dword2}; swap(pk(q2,q3), pk(q6,q7)) -> {dword1, dword3}.
        bf16x8 pa[4];
#pragma unroll
        for (int st = 0; st < 2; ++st) {
#pragma unroll
            for (int hh = 0; hh < 2; ++hh) {
                const f32x16& s_ = st ? sc1 : sc0;
                uint32_t a0 = pack_bf_trunc(s_[hh * 8 + 0], s_[hh * 8 + 1]);
                uint32_t a1 = pack_bf_trunc(s_[hh * 8 + 2], s_[hh * 8 + 3]);
                uint32_t a2 = pack_bf_trunc(s_[hh * 8 + 4], s_[hh * 8 + 5]);
                uint32_t a3 = pack_bf_trunc(s_[hh * 8 + 6], s_[hh * 8 + 7]);
                u32x2 r02 = __builtin_amdgcn_permlane32_swap(a0, a2, false, false);
                u32x2 r13 = __builtin_amdgcn_permlane32_swap(a1, a3, false, false);
                u32x4 pd = {r02[0], r13[0], r02[1], r13[1]};
                pa[st * 2 + hh] = __builtin_bit_cast(bf16x8, pd);
            }
        }

        // PV: o[dt] (C rows = t, cols = d = dt*32+lo), k-steps over s
        __builtin_amdgcn_s_setprio(1);
#pragma unroll
        for (int ks = 0; ks < 4; ++ks) {
            bf16x8 bv0 = *(const bf16x8*)&Vs[cur][(0 * 4 + ks) * 512 + lane * 8];
            o0 = __builtin_amdgcn_mfma_f32_32x32x16_bf16(pa[ks], bv0, o0, 0, 0, 0);
        }
#pragma unroll
        for (int ks = 0; ks < 4; ++ks) {
            bf16x8 bv1 = *(const bf16x8*)&Vs[cur][(1 * 4 + ks) * 512 + lane * 8];
            o1 = __builtin_amdgcn_mfma_f32_32x32x16_bf16(pa[ks], bv1, o1, 0, 0, 0);
        }
        __builtin_amdgcn_s_setprio(0);

        // one barrier/iter: drains prefetch + releases cur buffers
        __syncthreads();
    }

    // lane owns full row t = t_base + lo split with partner: combine halves
    lsum += __shfl_xor(lsum, 32, 64);
    float rinv = 1.0f / lsum;

    int b = bh >> 4, h = bh & 15;
    float inv[16];
#pragma unroll
    for (int r = 0; r < 16; ++r) {
        int rr = (r & 3) + 8 * (r >> 2) + 4 * hi;    // t-local of o[*][r]
        inv[r] = __shfl(rinv, rr, 64);               // lane rr holds that t
    }
#pragma unroll
    for (int r = 0; r < 16; ++r) {
        int t = t_base + (r & 3) + 8 * (r >> 2) + 4 * hi;
        size_t nrow = (size_t)(t * 2 + b) * KAUG + h * 64;
        ohg[nrow + lo]      = f2bf(o0[r] * inv[r]);
        ohg[nrow + 32 + lo] = f2bf(o1[r] * inv[r]);
    }
    if (lane < 32)
        lbuf[(size_t)bh * T_LEN + t_base + lane] = rinv;   // store 1/lsum
}

// ---------------------------------------------------------------------------
// attnw v6: 128t x 64s per block, grid = 1024 blocks. Q direct, K dbuf with
// next-head prefetch, one barrier/head, XCD-chunked swizzle, native exp2,
// lbuf holds 1/lsum (no rcp chain). No per-MFMA setprio (m190).
// ---------------------------------------------------------------------------
__global__ __launch_bounds__(256, 4) void attnw_mfma_kernel(
    const USH* __restrict__ qp, const USH* __restrict__ kp,
    const float* __restrict__ lbuf, float* __restrict__ aw) {
    __shared__ __align__(16) USH Ks[2][4096];

    int orig = blockIdx.x + (blockIdx.y << 5) + (blockIdx.z << 9);  // grid 32x16x2
    int v_ = ((orig & 7) << 7) + (orig >> 3);                       // 128 blocks/XCD
    int s0 = (v_ & 31) * 64, t0 = ((v_ >> 5) & 15) * 128, b = v_ >> 9;

    int tid = threadIdx.x, w = tid >> 6, lane = tid & 63;
    int quad = lane >> 4, l16 = lane & 15;

    const f32x4 fzero = {0.f, 0.f, 0.f, 0.f};
    f32x4 acc[2][4];
#pragma unroll
    for (int i2 = 0; i2 < 2; ++i2)
#pragma unroll
        for (int j = 0; j < 4; ++j) acc[i2][j] = fzero;

    // prologue: stage K for head 0
    {
        size_t head0 = (size_t)(b * 16) * (T_LEN * HD);
#pragma unroll
        for (int half = 0; half < 2; ++half)
            async_cp16(kp + head0 + (size_t)(s0 + w * 16 + l16) * HD + half * 32 + quad * 8,
                       &Ks[0][w * 1024 + half * 512]);
    }
    __syncthreads();

    for (int h = 0; h < N_HEADS; ++h) {
        int bh = b * 16 + h;
        size_t head = (size_t)bh * (T_LEN * HD);
        int cur = h & 1;

        // prefetch next head's K into the other buffer
        if (h + 1 < N_HEADS) {
            size_t headn = head + (size_t)(T_LEN * HD);
#pragma unroll
            for (int half = 0; half < 2; ++half)
                async_cp16(kp + headn + (size_t)(s0 + w * 16 + l16) * HD + half * 32 + quad * 8,
                           &Ks[cur ^ 1][w * 1024 + half * 512]);
        }

        // Q fragments direct from global (A-operand; rows are wave-private)
        bf16x8 aq[2][2];
#pragma unroll
        for (int i2 = 0; i2 < 2; ++i2) {
            int i = w * 2 + i2;
            const USH* qrow = qp + head + (size_t)(t0 + i * 16 + l16) * HD + quad * 8;
            aq[i2][0] = *(const bf16x8*)qrow;
            aq[i2][1] = *(const bf16x8*)(qrow + 32);
        }

        float il[2][4];
#pragma unroll
        for (int i2 = 0; i2 < 2; ++i2)
#pragma unroll
            for (int r = 0; r < 4; ++r) {
                int t = t0 + w * 32 + i2 * 16 + quad * 4 + r;
                il[i2][r] = lbuf[(size_t)bh * T_LEN + t];   // already 1/lsum
            }

        bf16x8 bk[4][2];
#pragma unroll
        for (int j = 0; j < 4; ++j)
#pragma unroll
            for (int half = 0; half < 2; ++half)
                bk[j][half] = *(const bf16x8*)&Ks[cur][j * 1024 + half * 512 + quad * 128 + l16 * 8];

#pragma unroll
        for (int i2 = 0; i2 < 2; ++i2) {
#pragma unroll
            for (int j = 0; j < 4; ++j) {
                f32x4 s = __builtin_amdgcn_mfma_f32_16x16x32_bf16(aq[i2][0], bk[j][0], fzero, 0, 0, 0);
                s = __builtin_amdgcn_mfma_f32_16x16x32_bf16(aq[i2][1], bk[j][1], s, 0, 0, 0);
#pragma unroll
                for (int r = 0; r < 4; ++r)
                    acc[i2][j][r] += __builtin_amdgcn_exp2f(s[r]) * il[i2][r];
            }
        }

        // single barrier: drains this head's prefetch + releases cur buffer
        __syncthreads();
    }

    const float inv_h = 1.0f / (float)N_HEADS;
#pragma unroll
    for (int i2 = 0; i2 < 2; ++i2)
#pragma unroll
        for (int j = 0; j < 4; ++j)
#pragma unroll
            for (int r = 0; r < 4; ++r) {
                int t = t0 + w * 32 + i2 * 16 + quad * 4 + r;
                aw[(size_t)b * T_LEN * S_LEN + (size_t)t * S_LEN + s0 + j * 16 + l16] =
                    acc[i2][j][r] * inv_h;
            }
}

// ---------------------------------------------------------------------------
extern "C" void kernel_launch(void* const* d_in, const int* in_sizes, int n_in,
                              void* d_out, int out_size, void* d_ws, size_t ws_size,
                              hipStream_t stream) {
    (void)in_sizes; (void)n_in; (void)out_size; (void)ws_size;

    const float* query = (const float*)d_in[0];
    const float* key_  = (const float*)d_in[1];
    const float* value = (const float*)d_in[2];
    const float* q_w = (const float*)d_in[3],  *q_b = (const float*)d_in[4];
    const float* q_la = (const float*)d_in[5], *q_lb = (const float*)d_in[6];
    const float* k_w = (const float*)d_in[7],  *k_b = (const float*)d_in[8];
    const float* k_la = (const float*)d_in[9], *k_lb = (const float*)d_in[10];
    const float* v_w = (const float*)d_in[11], *v_b = (const float*)d_in[12];
    const float* v_la = (const float*)d_in[13], *v_lb = (const float*)d_in[14];
    const float* o_w = (const float*)d_in[15], *o_b = (const float*)d_in[16];
    const float* o_la = (const float*)d_in[17], *o_lb = (const float*)d_in[18];

    USH* Xg   = (USH*)d_ws;                 // 3 * NROW*KAUG
    USH* Wg   = Xg + 3 * XG_N;              // 4 * E_DIM*KAUG
    USH* qkv  = Wg + 4 * WG_N;              // 3 * HSZ
    USH* qp   = qkv;
    USH* kp   = qkv + HSZ;
    USH* vpt  = qkv + 2 * HSZ;
    float* lbuf = (float*)(qkv + 3 * HSZ);

    float* out = (float*)d_out;                       // (T,B,E) fp32
    float* aw  = out + (size_t)T_LEN * B_SZ * E_DIM;  // (B,T,S) fp32

    dim3 blk(256);

    lora_aug_x3_kernel<<<dim3(NROW / 16, 3), blk, 0, stream>>>(
        query, key_, value, q_la, k_la, v_la, Xg);
    aug_w4_kernel<<<dim3(E_DIM, 4), blk, 0, stream>>>(
        q_w, q_lb, q_b, k_w, k_lb, k_b, v_w, v_lb, v_b, o_w, o_lb, o_b, Wg);
    gemm_qkv_kernel<<<dim3(E_DIM / 128, NROW / 128, 3), blk, 0, stream>>>(Xg, Wg, qkv);

    flash_mfma_kernel<<<dim3(T_LEN / 128, B_SZ * N_HEADS), blk, 0, stream>>>(
        qp, kp, vpt, Xg, lbuf);
    attnw_mfma_kernel<<<dim3(S_LEN / 64, T_LEN / 128, B_SZ), blk, 0, stream>>>(
        qp, kp, lbuf, aw);

    lora_a_bf16_kernel<<<NROW / 16, blk, 0, stream>>>(Xg, o_la);
    gemm_o_kernel<<<dim3(E_DIM / 128, NROW / 64), blk, 0, stream>>>(
        Xg, Wg + 3 * WG_N, out);
}

// Round 9
// 329.062 us; speedup vs baseline: 1.4367x; 1.0034x over previous
//
#include <hip/hip_runtime.h>
#include <stdint.h>

// Problem constants
#define E_DIM 1024
#define KAUG 1056            // 1024 + 16 (LoRA) + 1 (bias) + 15 pad
#define N_HEADS 16
#define HD 64
#define R_LORA 16
#define T_LEN 2048
#define B_SZ 2
#define S_LEN 2048
#define NROW 4096            // T*B == S*B
// q pre-scale: (1/sqrt(64)) * log2(e)  -> softmax becomes exp2(score)
#define Q_SCALE 0.1803368801111204f

#define XG_N ((size_t)NROW * KAUG)
#define WG_N ((size_t)E_DIM * KAUG)
#define HSZ  ((size_t)B_SZ * N_HEADS * T_LEN * HD)

typedef unsigned short USH;
typedef __bf16 bf16x8 __attribute__((ext_vector_type(8)));
typedef unsigned short ushort8 __attribute__((ext_vector_type(8)));
typedef float  f32x4  __attribute__((ext_vector_type(4)));
typedef float  f32x16 __attribute__((ext_vector_type(16)));
typedef unsigned int u32x2 __attribute__((ext_vector_type(2)));
typedef unsigned int u32x4 __attribute__((ext_vector_type(4)));

__device__ __forceinline__ USH f2bf(float f) {
    uint32_t u = __builtin_bit_cast(uint32_t, f);
    return (USH)((u + 0x7FFFu + ((u >> 16) & 1u)) >> 16);
}
__device__ __forceinline__ float bf2f(USH s) {
    uint32_t u = ((uint32_t)s) << 16;
    return __builtin_bit_cast(float, u);
}
__device__ __forceinline__ void async_cp16(const void* g, void* l) {
    __builtin_amdgcn_global_load_lds(
        (const __attribute__((address_space(1))) void*)g,
        (__attribute__((address_space(3))) void*)l, 16, 0, 0);
}
// pack hi16(x), hi16(y) -> dword (bf16 truncation; y in high half)
__device__ __forceinline__ uint32_t pack_bf_trunc(float x, float y) {
    return __builtin_amdgcn_perm(__builtin_bit_cast(uint32_t, y),
                                 __builtin_bit_cast(uint32_t, x), 0x07060302u);
}
// 8 floats -> bf16x8 with RNE rounding (matches f2bf store path)
__device__ __forceinline__ bf16x8 cvt8(float4 a, float4 b) {
    ushort8 u;
    u[0] = f2bf(a.x); u[1] = f2bf(a.y); u[2] = f2bf(a.z); u[3] = f2bf(a.w);
    u[4] = f2bf(b.x); u[5] = f2bf(b.y); u[6] = f2bf(b.z); u[7] = f2bf(b.w);
    return __builtin_bit_cast(bf16x8, u);
}

// ---------------------------------------------------------------------------
// lora_aug v2: MFMA-based. Block = 16 rows, 4 waves K-split (256 k each).
// ---------------------------------------------------------------------------
__global__ __launch_bounds__(256) void lora_aug_x3_kernel(
    const float* __restrict__ Xq, const float* __restrict__ Xk,
    const float* __restrict__ Xv,
    const float* __restrict__ laq, const float* __restrict__ lak,
    const float* __restrict__ lav, USH* __restrict__ Xg_base) {
    int n0 = blockIdx.x * 16, y = blockIdx.y, tid = threadIdx.x;
    const float* X  = (y == 0) ? Xq : (y == 1) ? Xk : Xv;
    const float* la = (y == 0) ? laq : (y == 1) ? lak : lav;
    USH* Xg = Xg_base + (size_t)y * XG_N;

    int w = tid >> 6, lane = tid & 63, quad = lane >> 4, l16 = lane & 15;

    const float* xrow = X + (size_t)(n0 + l16) * E_DIM;
    const float* lrow = la + (size_t)l16 * E_DIM;
    USH* grow = Xg + (size_t)(n0 + l16) * KAUG;

    const f32x4 fzero = {0.f, 0.f, 0.f, 0.f};
    f32x4 acc = fzero;

#pragma unroll
    for (int i = 0; i < 8; ++i) {
        int k = w * 256 + i * 32 + quad * 8;
        bf16x8 af = cvt8(*(const float4*)(xrow + k), *(const float4*)(xrow + k + 4));
        *(bf16x8*)(grow + k) = af;                       // bf16 cast-write
        bf16x8 bf_ = cvt8(*(const float4*)(lrow + k), *(const float4*)(lrow + k + 4));
        acc = __builtin_amdgcn_mfma_f32_16x16x32_bf16(af, bf_, acc, 0, 0, 0);
    }

    // combine 4 wave-partials: acc[r] = XA[row = quad*4+r][col = l16] partial
    __shared__ float red[4][16][17];
#pragma unroll
    for (int r = 0; r < 4; ++r) red[w][quad * 4 + r][l16] = acc[r];
    __syncthreads();

    int row = tid >> 4, col = tid & 15;
    float v = red[0][row][col] + red[1][row][col] + red[2][row][col] + red[3][row][col];
    USH* trow = Xg + (size_t)(n0 + row) * KAUG + 1024;
    trow[col] = f2bf(v);                                 // XA cols 1024..1039
    trow[16 + col] = (col == 0) ? f2bf(1.0f) : (USH)0;   // bias col 1040, pad 0
}

// ---------------------------------------------------------------------------
// lora_a v2 (O-input tails): same MFMA structure; A-frags load bf16 Xg rows
// directly (already cast by flash). grid (NROW/16) = 256 blocks.
// ---------------------------------------------------------------------------
__global__ __launch_bounds__(256) void lora_a_bf16_kernel(
    USH* __restrict__ Xg, const float* __restrict__ la) {
    int n0 = blockIdx.x * 16, tid = threadIdx.x;
    int w = tid >> 6, lane = tid & 63, quad = lane >> 4, l16 = lane & 15;

    const USH* grow = Xg + (size_t)(n0 + l16) * KAUG;
    const float* lrow = la + (size_t)l16 * E_DIM;

    const f32x4 fzero = {0.f, 0.f, 0.f, 0.f};
    f32x4 acc = fzero;

#pragma unroll
    for (int i = 0; i < 8; ++i) {
        int k = w * 256 + i * 32 + quad * 8;
        bf16x8 af = *(const bf16x8*)(grow + k);
        bf16x8 bf_ = cvt8(*(const float4*)(lrow + k), *(const float4*)(lrow + k + 4));
        acc = __builtin_amdgcn_mfma_f32_16x16x32_bf16(af, bf_, acc, 0, 0, 0);
    }

    __shared__ float red[4][16][17];
#pragma unroll
    for (int r = 0; r < 4; ++r) red[w][quad * 4 + r][l16] = acc[r];
    __syncthreads();

    int row = tid >> 4, col = tid & 15;
    float v = red[0][row][col] + red[1][row][col] + red[2][row][col] + red[3][row][col];
    USH* trow = Xg + (size_t)(n0 + row) * KAUG + 1024;
    trow[col] = f2bf(v);
    trow[16 + col] = (col == 0) ? f2bf(1.0f) : (USH)0;
}

// ---------------------------------------------------------------------------
// Fused weight augment for all four projections. grid (E_DIM, 4): q,k,v,o.
// ---------------------------------------------------------------------------
__global__ __launch_bounds__(256) void aug_w4_kernel(
    const float* __restrict__ Wq, const float* __restrict__ lbq, const float* __restrict__ bq,
    const float* __restrict__ Wk, const float* __restrict__ lbk, const float* __restrict__ bk_,
    const float* __restrict__ Wv, const float* __restrict__ lbv, const float* __restrict__ bv_,
    const float* __restrict__ Wo, const float* __restrict__ lbo, const float* __restrict__ bo,
    USH* __restrict__ Wg_base) {
    int e = blockIdx.x, y = blockIdx.y, tid = threadIdx.x;
    const float* W    = (y == 0) ? Wq : (y == 1) ? Wk : (y == 2) ? Wv : Wo;
    const float* lb   = (y == 0) ? lbq : (y == 1) ? lbk : (y == 2) ? lbv : lbo;
    const float* bias = (y == 0) ? bq : (y == 1) ? bk_ : (y == 2) ? bv_ : bo;
    USH* Wg = Wg_base + (size_t)y * WG_N;

    float4 v = *(const float4*)(W + (size_t)e * E_DIM + tid * 4);
    ushort4 o;
    o.x = f2bf(v.x); o.y = f2bf(v.y); o.z = f2bf(v.z); o.w = f2bf(v.w);
    *(ushort4*)(Wg + (size_t)e * KAUG + tid * 4) = o;
    if (tid < 32) {
        float t = (tid < R_LORA) ? lb[(size_t)e * R_LORA + tid]
                                 : (tid == R_LORA ? bias[e] : 0.0f);
        Wg[(size_t)e * KAUG + 1024 + tid] = f2bf(t);
    }
}

// ---------------------------------------------------------------------------
// Batched q/k/v GEMM, 128x128 tile, grid (8, 32, 3) = 768. Double-buffered
// LDS + prefetch-before-compute + ONE barrier per K-step.
// ---------------------------------------------------------------------------
__global__ __launch_bounds__(256) void gemm_qkv_kernel(
    const USH* __restrict__ Xg_base, const USH* __restrict__ Wg_base,
    USH* __restrict__ qkv_base) {
    __shared__ __align__(16) USH As[2][128 * 32];
    __shared__ __align__(16) USH Bs[2][128 * 32];

    int orig = blockIdx.x + (blockIdx.y << 3) + blockIdx.z * 256;   // grid 8x32x3
    int v_ = (orig & 7) * 96 + (orig >> 3);                          // bijective, 768%8==0
    int e0 = (v_ & 7) * 128, n0 = ((v_ >> 3) & 31) * 128, z = v_ >> 8;

    const USH* Xg = Xg_base + (size_t)z * XG_N;
    const USH* Wg = Wg_base + (size_t)z * WG_N;
    USH* out = qkv_base + (size_t)z * HSZ;
    float scale = (z == 0) ? Q_SCALE : 1.0f;

    int tid = threadIdx.x;
    int wid = tid >> 6, lane = tid & 63, quad = lane >> 4, l16 = lane & 15;
    int wm = wid & 1, wn = wid >> 1;

    int r0 = wid * 16 + (lane >> 2);
    int k8 = (lane & 3) * 8;

    f32x4 acc[4][4];
    const f32x4 fzero = {0.f, 0.f, 0.f, 0.f};
#pragma unroll
    for (int i = 0; i < 4; ++i)
#pragma unroll
        for (int j = 0; j < 4; ++j) acc[i][j] = fzero;

    // prologue: stage kt=0 into buf 0
    async_cp16(Xg + (size_t)(n0 + r0) * KAUG + k8,       As[0] + (wid * 16) * 32);
    async_cp16(Xg + (size_t)(n0 + 64 + r0) * KAUG + k8,  As[0] + (64 + wid * 16) * 32);
    async_cp16(Wg + (size_t)(e0 + r0) * KAUG + k8,       Bs[0] + (wid * 16) * 32);
    async_cp16(Wg + (size_t)(e0 + 64 + r0) * KAUG + k8,  Bs[0] + (64 + wid * 16) * 32);
    __syncthreads();

    int cur = 0;
    for (int kt = 0; kt < KAUG; kt += 32, cur ^= 1) {
        if (kt + 32 < KAUG) {
            int kn = kt + 32;
            async_cp16(Xg + (size_t)(n0 + r0) * KAUG + kn + k8,       As[cur ^ 1] + (wid * 16) * 32);
            async_cp16(Xg + (size_t)(n0 + 64 + r0) * KAUG + kn + k8,  As[cur ^ 1] + (64 + wid * 16) * 32);
            async_cp16(Wg + (size_t)(e0 + r0) * KAUG + kn + k8,       Bs[cur ^ 1] + (wid * 16) * 32);
            async_cp16(Wg + (size_t)(e0 + 64 + r0) * KAUG + kn + k8,  Bs[cur ^ 1] + (64 + wid * 16) * 32);
        }

        bf16x8 af[4], bfr[4];
#pragma unroll
        for (int i = 0; i < 4; ++i)
            af[i] = *(const bf16x8*)&As[cur][(wm * 64 + i * 16 + l16) * 32 + quad * 8];
#pragma unroll
        for (int j = 0; j < 4; ++j)
            bfr[j] = *(const bf16x8*)&Bs[cur][(wn * 64 + j * 16 + l16) * 32 + quad * 8];
#pragma unroll
        for (int i = 0; i < 4; ++i)
#pragma unroll
            for (int j = 0; j < 4; ++j)
                acc[i][j] = __builtin_amdgcn_mfma_f32_16x16x32_bf16(
                    af[i], bfr[j], acc[i][j], 0, 0, 0);

        // one barrier: drains prefetch (landed under compute) + releases cur
        __syncthreads();
    }

#pragma unroll
    for (int i = 0; i < 4; ++i) {
#pragma unroll
        for (int j = 0; j < 4; ++j) {
#pragma unroll
            for (int r = 0; r < 4; ++r) {
                int nr = n0 + wm * 64 + i * 16 + quad * 4 + r;
                int ec = e0 + wn * 64 + j * 16 + l16;
                float v = acc[i][j][r] * scale;
                int b = nr & 1, h = ec >> 6, d = ec & 63;
                if (z != 2) {
                    int t = nr >> 1;
                    out[(((size_t)(b * 16 + h) * T_LEN + t) << 6) + d] = f2bf(v);
                } else {
                    int s = nr >> 1;
                    out[(((size_t)(b * 16 + h) * HD + d) << 11) + s] = f2bf(v);
                }
            }
        }
    }
}

// ---------------------------------------------------------------------------
// O-projection GEMM -> fp32 d_out. grid (8, 64) = 512 blocks. Pipelined
// single-barrier loop (dbuf LDS: 2x(4+8) = 24 KB).
// ---------------------------------------------------------------------------
__global__ __launch_bounds__(256) void gemm_o_kernel(
    const USH* __restrict__ Xg, const USH* __restrict__ Wg,
    float* __restrict__ out) {
    __shared__ __align__(16) USH As[2][64 * 32];
    __shared__ __align__(16) USH Bs[2][128 * 32];

    int orig = blockIdx.x + (blockIdx.y << 3);          // grid 8x64
    int v_ = ((orig & 7) << 6) + (orig >> 3);           // 64 blocks/XCD
    int e0 = (v_ & 7) * 128, n0 = (v_ >> 3) * 64;

    int tid = threadIdx.x;
    int wid = tid >> 6, lane = tid & 63, quad = lane >> 4, l16 = lane & 15;
    int wm = wid & 1, wn = wid >> 1;
    int r0 = wid * 16 + (lane >> 2);
    int k8 = (lane & 3) * 8;

    f32x4 acc[2][4];
    const f32x4 fzero = {0.f, 0.f, 0.f, 0.f};
#pragma unroll
    for (int i = 0; i < 2; ++i)
#pragma unroll
        for (int j = 0; j < 4; ++j) acc[i][j] = fzero;

    // prologue: stage kt=0 into buf 0
    async_cp16(Xg + (size_t)(n0 + r0) * KAUG + k8,       As[0] + (wid * 16) * 32);
    async_cp16(Wg + (size_t)(e0 + r0) * KAUG + k8,       Bs[0] + (wid * 16) * 32);
    async_cp16(Wg + (size_t)(e0 + 64 + r0) * KAUG + k8,  Bs[0] + (64 + wid * 16) * 32);
    __syncthreads();

    int cur = 0;
    for (int kt = 0; kt < KAUG; kt += 32, cur ^= 1) {
        if (kt + 32 < KAUG) {
            int kn = kt + 32;
            async_cp16(Xg + (size_t)(n0 + r0) * KAUG + kn + k8,       As[cur ^ 1] + (wid * 16) * 32);
            async_cp16(Wg + (size_t)(e0 + r0) * KAUG + kn + k8,       Bs[cur ^ 1] + (wid * 16) * 32);
            async_cp16(Wg + (size_t)(e0 + 64 + r0) * KAUG + kn + k8,  Bs[cur ^ 1] + (64 + wid * 16) * 32);
        }

        bf16x8 af[2], bfr[4];
#pragma unroll
        for (int i = 0; i < 2; ++i)
            af[i] = *(const bf16x8*)&As[cur][(wm * 32 + i * 16 + l16) * 32 + quad * 8];
#pragma unroll
        for (int j = 0; j < 4; ++j)
            bfr[j] = *(const bf16x8*)&Bs[cur][(wn * 64 + j * 16 + l16) * 32 + quad * 8];
#pragma unroll
        for (int i = 0; i < 2; ++i)
#pragma unroll
            for (int j = 0; j < 4; ++j)
                acc[i][j] = __builtin_amdgcn_mfma_f32_16x16x32_bf16(
                    af[i], bfr[j], acc[i][j], 0, 0, 0);

        __syncthreads();
    }

#pragma unroll
    for (int i = 0; i < 2; ++i)
#pragma unroll
        for (int j = 0; j < 4; ++j)
#pragma unroll
            for (int r = 0; r < 4; ++r) {
                int nr = n0 + wm * 32 + i * 16 + quad * 4 + r;
                int ec = e0 + wn * 64 + j * 16 + l16;
                out[(size_t)nr * E_DIM + ec] = acc[i][j][r];
            }
}

// ---------------------------------------------------------------------------
// Flash v14 = v13 + in-register PV-lag (T15, 2-state). PV(i-1) consumes
// pa_prev (registers) and V(i-1): it is INDEPENDENT of QK(i)'s result, so
// its 8 MFMAs fill the matrix pipe while exp2(i)/pack(i) run on the VALU
// pipe (separate pipes). V staging shifts one iter late (stage V(i) at
// iter i into Vs[i&1], consumed at i+1 from Vs[i&1]) so the double buffer
// never stages into the half PV is reading. K staging stays one ahead.
// All pa indices static (rule #20). Epilogue drains PV(31).
// 4 waves x 32 t-rows, grid (T/128, B*H) = 512 blocks, LDS 32 KB.
// ---------------------------------------------------------------------------
__global__ __launch_bounds__(256, 2) void flash_mfma_kernel(
    const USH* __restrict__ qp, const USH* __restrict__ kp,
    const USH* __restrict__ vpt, USH* __restrict__ ohg,
    float* __restrict__ lbuf) {
    __shared__ __align__(16) USH Ks[2][4096];   // 8 frags x 512 USH (1KB each)
    __shared__ __align__(16) USH Vs[2][4096];

    int orig = blockIdx.x + (blockIdx.y << 4);  // grid 16x32
    int v_ = ((orig & 7) << 6) + (orig >> 3);   // 64 blocks/XCD chunk
    int t0 = (v_ & 15) * 128, bh = v_ >> 4;     // chunk c -> heads [4c, 4c+4)

    int tid = threadIdx.x, w = tid >> 6, lane = tid & 63;
    int lo = lane & 31, hi = lane >> 5;
    size_t headO = (size_t)bh * (T_LEN * HD);
    int t_base = t0 + w * 32;

    // Q fragments direct from global (B-operand: n=t=lo, k=kb*16+hi*8+e)
    bf16x8 bq[4];
    {
        const USH* qrow = qp + headO + (size_t)(t_base + lo) * HD + hi * 8;
#pragma unroll
        for (int kb = 0; kb < 4; ++kb)
            bq[kb] = *(const bf16x8*)(qrow + kb * 16);
    }

    // prologue: stage K[0] only (V[0] staged inside iter 0).
    // Frag f: K rows (f>>2)*32+lo, k (f&3)*16+hi*8. Wave w -> f=2w,2w+1.
#pragma unroll
    for (int c = 0; c < 2; ++c) {
        int f = w * 2 + c;
        async_cp16(kp + headO + (size_t)((f >> 2) * 32 + lo) * HD + (f & 3) * 16 + hi * 8,
                   &Ks[0][f * 512]);
    }
    __syncthreads();

    const f32x16 z16 = {0,0,0,0,0,0,0,0,0,0,0,0,0,0,0,0};
    f32x16 o0 = z16, o1 = z16;
    float lsum = 0.f;
    bf16x8 pa_prev[4];          // P(i-1) A-frags, static-indexed (rule #20)

    for (int it = 0; it < S_LEN / 64; ++it) {
        int cur = it & 1;
        // prefetch K[it+1] -> Ks[cur^1]; stage V[it] -> Vs[cur]
        // (PV(it-1) reads Vs[cur^1] -- disjoint from both targets)
        if (it + 1 < S_LEN / 64) {
            int sn = (it + 1) * 64;
#pragma unroll
            for (int c = 0; c < 2; ++c) {
                int f = w * 2 + c;
                async_cp16(kp + headO + (size_t)(sn + (f >> 2) * 32 + lo) * HD + (f & 3) * 16 + hi * 8,
                           &Ks[cur ^ 1][f * 512]);
            }
        }
        {
            int s0 = it * 64;
#pragma unroll
            for (int c = 0; c < 2; ++c) {
                int f = w * 2 + c;
                async_cp16(vpt + headO + (size_t)((f >> 2) * 32 + lo) * S_LEN + s0 + (f & 3) * 16 + hi * 8,
                           &Vs[cur][f * 512]);
            }
        }

        // QK^T swapped: sc[st] = 32x32 tile, C[row=s_local][col=t_local=lo]
        f32x16 sc0 = z16, sc1 = z16;
        __builtin_amdgcn_s_setprio(1);
#pragma unroll
        for (int kb = 0; kb < 4; ++kb) {
            bf16x8 ak0 = *(const bf16x8*)&Ks[cur][(0 * 4 + kb) * 512 + lane * 8];
            sc0 = __builtin_amdgcn_mfma_f32_32x32x16_bf16(ak0, bq[kb], sc0, 0, 0, 0);
        }
#pragma unroll
        for (int kb = 0; kb < 4; ++kb) {
            bf16x8 ak1 = *(const bf16x8*)&Ks[cur][(1 * 4 + kb) * 512 + lane * 8];
            sc1 = __builtin_amdgcn_mfma_f32_32x32x16_bf16(ak1, bq[kb], sc1, 0, 0, 0);
        }

        // PV(it-1): pa_prev (regs) x V(it-1) from Vs[cur^1]. Independent of
        // sc0/sc1 -> issues on the MFMA pipe while exp2 below runs on VALU.
        if (it > 0) {
#pragma unroll
            for (int ks = 0; ks < 4; ++ks) {
                bf16x8 bv0 = *(const bf16x8*)&Vs[cur ^ 1][(0 * 4 + ks) * 512 + lane * 8];
                o0 = __builtin_amdgcn_mfma_f32_32x32x16_bf16(pa_prev[ks], bv0, o0, 0, 0, 0);
            }
#pragma unroll
            for (int ks = 0; ks < 4; ++ks) {
                bf16x8 bv1 = *(const bf16x8*)&Vs[cur ^ 1][(1 * 4 + ks) * 512 + lane * 8];
                o1 = __builtin_amdgcn_mfma_f32_32x32x16_bf16(pa_prev[ks], bv1, o1, 0, 0, 0);
            }
        }
        __builtin_amdgcn_s_setprio(0);

        // softmax(it): exp2 in place, partial sums
        float ls0 = 0.f, ls1 = 0.f, ls2 = 0.f, ls3 = 0.f;
#pragma unroll
        for (int r = 0; r < 16; ++r) {
            float p0 = __builtin_amdgcn_exp2f(sc0[r]);
            float p1 = __builtin_amdgcn_exp2f(sc1[r]);
            sc0[r] = p0; sc1[r] = p1;
            if ((r & 3) == 0)      { ls0 += p0; ls0 += p1; }
            else if ((r & 3) == 1) { ls1 += p0; ls1 += p1; }
            else if ((r & 3) == 2) { ls2 += p0; ls2 += p1; }
            else                   { ls3 += p0; ls3 += p1; }
        }
        lsum += (ls0 + ls1) + (ls2 + ls3);

        // P(it) -> pa_prev for next iter (T12 cvt_pk + permlane32_swap)
#pragma unroll
        for (int st = 0; st < 2; ++st) {
#pragma unroll
            for (int hh = 0; hh < 2; ++hh) {
                const f32x16& s_ = st ? sc1 : sc0;
                uint32_t a0 = pack_bf_trunc(s_[hh * 8 + 0], s_[hh * 8 + 1]);
                uint32_t a1 = pack_bf_trunc(s_[hh * 8 + 2], s_[hh * 8 + 3]);
                uint32_t a2 = pack_bf_trunc(s_[hh * 8 + 4], s_[hh * 8 + 5]);
                uint32_t a3 = pack_bf_trunc(s_[hh * 8 + 6], s_[hh * 8 + 7]);
                u32x2 r02 = __builtin_amdgcn_permlane32_swap(a0, a2, false, false);
                u32x2 r13 = __builtin_amdgcn_permlane32_swap(a1, a3, false, false);
                u32x4 pd = {r02[0], r13[0], r02[1], r13[1]};
                pa_prev[st * 2 + hh] = __builtin_bit_cast(bf16x8, pd);
            }
        }

        // one barrier/iter: drains K[it+1] + V[it] staging, releases buffers
        __syncthreads();
    }

    // epilogue: PV(31) from Vs[(31)&1] = Vs[1]
    {
#pragma unroll
        for (int ks = 0; ks < 4; ++ks) {
            bf16x8 bv0 = *(const bf16x8*)&Vs[1][(0 * 4 + ks) * 512 + lane * 8];
            o0 = __builtin_amdgcn_mfma_f32_32x32x16_bf16(pa_prev[ks], bv0, o0, 0, 0, 0);
        }
#pragma unroll
        for (int ks = 0; ks < 4; ++ks) {
            bf16x8 bv1 = *(const bf16x8*)&Vs[1][(1 * 4 + ks) * 512 + lane * 8];
            o1 = __builtin_amdgcn_mfma_f32_32x32x16_bf16(pa_prev[ks], bv1, o1, 0, 0, 0);
        }
    }

    // lane owns full row t = t_base + lo split with partner: combine halves
    lsum += __shfl_xor(lsum, 32, 64);
    float rinv = 1.0f / lsum;

    int b = bh >> 4, h = bh & 15;
    float inv[16];
#pragma unroll
    for (int r = 0; r < 16; ++r) {
        int rr = (r & 3) + 8 * (r >> 2) + 4 * hi;    // t-local of o[*][r]
        inv[r] = __shfl(rinv, rr, 64);               // lane rr holds that t
    }
#pragma unroll
    for (int r = 0; r < 16; ++r) {
        int t = t_base + (r & 3) + 8 * (r >> 2) + 4 * hi;
        size_t nrow = (size_t)(t * 2 + b) * KAUG + h * 64;
        ohg[nrow + lo]      = f2bf(o0[r] * inv[r]);
        ohg[nrow + 32 + lo] = f2bf(o1[r] * inv[r]);
    }
    if (lane < 32)
        lbuf[(size_t)bh * T_LEN + t_base + lane] = rinv;   // store 1/lsum
}

// ---------------------------------------------------------------------------
// attnw v6: 128t x 64s per block, grid = 1024 blocks. Q direct, K dbuf with
// next-head prefetch, one barrier/head, XCD-chunked swizzle, native exp2,
// lbuf holds 1/lsum (no rcp chain). No per-MFMA setprio (m190).
// ---------------------------------------------------------------------------
__global__ __launch_bounds__(256, 4) void attnw_mfma_kernel(
    const USH* __restrict__ qp, const USH* __restrict__ kp,
    const float* __restrict__ lbuf, float* __restrict__ aw) {
    __shared__ __align__(16) USH Ks[2][4096];

    int orig = blockIdx.x + (blockIdx.y << 5) + (blockIdx.z << 9);  // grid 32x16x2
    int v_ = ((orig & 7) << 7) + (orig >> 3);                       // 128 blocks/XCD
    int s0 = (v_ & 31) * 64, t0 = ((v_ >> 5) & 15) * 128, b = v_ >> 9;

    int tid = threadIdx.x, w = tid >> 6, lane = tid & 63;
    int quad = lane >> 4, l16 = lane & 15;

    const f32x4 fzero = {0.f, 0.f, 0.f, 0.f};
    f32x4 acc[2][4];
#pragma unroll
    for (int i2 = 0; i2 < 2; ++i2)
#pragma unroll
        for (int j = 0; j < 4; ++j) acc[i2][j] = fzero;

    // prologue: stage K for head 0
    {
        size_t head0 = (size_t)(b * 16) * (T_LEN * HD);
#pragma unroll
        for (int half = 0; half < 2; ++half)
            async_cp16(kp + head0 + (size_t)(s0 + w * 16 + l16) * HD + half * 32 + quad * 8,
                       &Ks[0][w * 1024 + half * 512]);
    }
    __syncthreads();

    for (int h = 0; h < N_HEADS; ++h) {
        int bh = b * 16 + h;
        size_t head = (size_t)bh * (T_LEN * HD);
        int cur = h & 1;

        // prefetch next head's K into the other buffer
        if (h + 1 < N_HEADS) {
            size_t headn = head + (size_t)(T_LEN * HD);
#pragma unroll
            for (int half = 0; half < 2; ++half)
                async_cp16(kp + headn + (size_t)(s0 + w * 16 + l16) * HD + half * 32 + quad * 8,
                           &Ks[cur ^ 1][w * 1024 + half * 512]);
        }

        // Q fragments direct from global (A-operand; rows are wave-private)
        bf16x8 aq[2][2];
#pragma unroll
        for (int i2 = 0; i2 < 2; ++i2) {
            int i = w * 2 + i2;
            const USH* qrow = qp + head + (size_t)(t0 + i * 16 + l16) * HD + quad * 8;
            aq[i2][0] = *(const bf16x8*)qrow;
            aq[i2][1] = *(const bf16x8*)(qrow + 32);
        }

        float il[2][4];
#pragma unroll
        for (int i2 = 0; i2 < 2; ++i2)
#pragma unroll
            for (int r = 0; r < 4; ++r) {
                int t = t0 + w * 32 + i2 * 16 + quad * 4 + r;
                il[i2][r] = lbuf[(size_t)bh * T_LEN + t];   // already 1/lsum
            }

        bf16x8 bk[4][2];
#pragma unroll
        for (int j = 0; j < 4; ++j)
#pragma unroll
            for (int half = 0; half < 2; ++half)
                bk[j][half] = *(const bf16x8*)&Ks[cur][j * 1024 + half * 512 + quad * 128 + l16 * 8];

#pragma unroll
        for (int i2 = 0; i2 < 2; ++i2) {
#pragma unroll
            for (int j = 0; j < 4; ++j) {
                f32x4 s = __builtin_amdgcn_mfma_f32_16x16x32_bf16(aq[i2][0], bk[j][0], fzero, 0, 0, 0);
                s = __builtin_amdgcn_mfma_f32_16x16x32_bf16(aq[i2][1], bk[j][1], s, 0, 0, 0);
#pragma unroll
                for (int r = 0; r < 4; ++r)
                    acc[i2][j][r] += __builtin_amdgcn_exp2f(s[r]) * il[i2][r];
            }
        }

        // single barrier: drains this head's prefetch + releases cur buffer
        __syncthreads();
    }

    const float inv_h = 1.0f / (float)N_HEADS;
#pragma unroll
    for (int i2 = 0; i2 < 2; ++i2)
#pragma unroll
        for (int j = 0; j < 4; ++j)
#pragma unroll
            for (int r = 0; r < 4; ++r) {
                int t = t0 + w * 32 + i2 * 16 + quad * 4 + r;
                aw[(size_t)b * T_LEN * S_LEN + (size_t)t * S_LEN + s0 + j * 16 + l16] =
                    acc[i2][j][r] * inv_h;
            }
}

// ---------------------------------------------------------------------------
extern "C" void kernel_launch(void* const* d_in, const int* in_sizes, int n_in,
                              void* d_out, int out_size, void* d_ws, size_t ws_size,
                              hipStream_t stream) {
    (void)in_sizes; (void)n_in; (void)out_size; (void)ws_size;

    const float* query = (const float*)d_in[0];
    const float* key_  = (const float*)d_in[1];
    const float* value = (const float*)d_in[2];
    const float* q_w = (const float*)d_in[3],  *q_b = (const float*)d_in[4];
    const float* q_la = (const float*)d_in[5], *q_lb = (const float*)d_in[6];
    const float* k_w = (const float*)d_in[7],  *k_b = (const float*)d_in[8];
    const float* k_la = (const float*)d_in[9], *k_lb = (const float*)d_in[10];
    const float* v_w = (const float*)d_in[11], *v_b = (const float*)d_in[12];
    const float* v_la = (const float*)d_in[13], *v_lb = (const float*)d_in[14];
    const float* o_w = (const float*)d_in[15], *o_b = (const float*)d_in[16];
    const float* o_la = (const float*)d_in[17], *o_lb = (const float*)d_in[18];

    USH* Xg   = (USH*)d_ws;                 // 3 * NROW*KAUG
    USH* Wg   = Xg + 3 * XG_N;              // 4 * E_DIM*KAUG
    USH* qkv  = Wg + 4 * WG_N;              // 3 * HSZ
    USH* qp   = qkv;
    USH* kp   = qkv + HSZ;
    USH* vpt  = qkv + 2 * HSZ;
    float* lbuf = (float*)(qkv + 3 * HSZ);

    float* out = (float*)d_out;                       // (T,B,E) fp32
    float* aw  = out + (size_t)T_LEN * B_SZ * E_DIM;  // (B,T,S) fp32

    dim3 blk(256);

    lora_aug_x3_kernel<<<dim3(NROW / 16, 3), blk, 0, stream>>>(
        query, key_, value, q_la, k_la, v_la, Xg);
    aug_w4_kernel<<<dim3(E_DIM, 4), blk, 0, stream>>>(
        q_w, q_lb, q_b, k_w, k_lb, k_b, v_w, v_lb, v_b, o_w, o_lb, o_b, Wg);
    gemm_qkv_kernel<<<dim3(E_DIM / 128, NROW / 128, 3), blk, 0, stream>>>(Xg, Wg, qkv);

    flash_mfma_kernel<<<dim3(T_LEN / 128, B_SZ * N_HEADS), blk, 0, stream>>>(
        qp, kp, vpt, Xg, lbuf);
    attnw_mfma_kernel<<<dim3(S_LEN / 64, T_LEN / 128, B_SZ), blk, 0, stream>>>(
        qp, kp, lbuf, aw);

    lora_a_bf16_kernel<<<NROW / 16, blk, 0, stream>>>(Xg, o_la);
    gemm_o_kernel<<<dim3(E_DIM / 128, NROW / 64), blk, 0, stream>>>(
        Xg, Wg + 3 * WG_N, out);
}